// Round 1
// baseline (6198.134 us; speedup 1.0000x reference)
//
#include <hip/hip_runtime.h>
#include <hip/hip_bf16.h>

// ============================================================================
// PPO agent fused forward:
//   actor(states) -> probs[ T,18 ]          (Linear-LN-ReLU x2 + Linear + softmax)
//   critic(states), critic(next_states) -> values, next_values
//   deltas = rewards + 0.99*nv*mask - v ;  GAE reverse scan ; returns = adv + v
// Output [T,20] = [probs | adv | ret]
//
// Design (round 1, correctness-first):
//  - bf16 MFMA 16x16x32, fp32 accum. Weights pre-converted to bf16 and
//    transposed to [N][K] in ws (prep kernel) so B-frags are 2x 8B loads.
//  - 4 waves/block, each wave owns 16 rows x all 256 cols -> LN reduction is
//    in-wave shfl_xor; no __syncthreads anywhere in the main kernel.
//  - Activations in 8KB/wave LDS slice, XOR-swizzled (byte ^= (row&15)<<3).
//  - GAE: decay (0.9405)^512 ~ 4e-13 -> chunk-parallel scan with 512 lookahead.
// ============================================================================

#define T_SZ 524288
#define GL 0.9405f   // GAMMA*LAM

typedef __attribute__((ext_vector_type(8))) short bf16x8;   // 8 bf16 (4 VGPRs)
typedef __attribute__((ext_vector_type(4))) float f32x4;

// ws layout (bf16 elements)
#define OFF_AW1T 0        // [256][64]
#define OFF_AW2T 16384    // [256][256]
#define OFF_AW3T 81920    // [32][256]  rows >=18 zero
#define OFF_CW1T 90112    // [256][64]
#define OFF_CW2T 106496   // [256][256]
#define OFF_CW3T 172032   // [16][256]  rows >=1 zero
#define W_ELEMS  176128
#define OFF_DELTAS_BYTES 352256

// ---------------------------------------------------------------------------
__device__ __forceinline__ void* lds_at(void* base, int row, int colByte, int strideB) {
  // XOR swizzle spreads 8B chunks of different rows across banks (keeps 8B align)
  return (char*)base + row * strideB + (colByte ^ ((row & 15) << 3));
}

union FragU { unsigned long long u[2]; bf16x8 v; };

__device__ __forceinline__ bf16x8 mk_frag(const void* p0, const void* p1) {
  FragU t;
  t.u[0] = *(const unsigned long long*)p0;  // k-block 0 (k .. k+3)
  t.u[1] = *(const unsigned long long*)p1;  // k-block 1 (k+16 .. k+19)
  return t.v;
}

// A from swizzled LDS (rows = lane&15), B from global Wt[N][K] bf16.
// acc[nt] holds D(row=(lane>>4)*4+reg, col=nt*16+(lane&15)).
template<int K, int NT>
__device__ __forceinline__ void run_gemm(void* A0, int astrB,
                                         const __hip_bfloat16* __restrict__ Wt,
                                         int c, int q, f32x4* acc) {
#pragma unroll
  for (int nt = 0; nt < NT; ++nt) acc[nt] = (f32x4){0.f, 0.f, 0.f, 0.f};
#pragma unroll
  for (int ks = 0; ks < K / 32; ++ks) {
    const int k0 = ks * 32 + q * 4;
    bf16x8 a = mk_frag(lds_at(A0, c, k0 * 2, astrB),
                       lds_at(A0, c, (k0 + 16) * 2, astrB));
#pragma unroll
    for (int nt = 0; nt < NT; ++nt) {
      const __hip_bfloat16* wp = Wt + (nt * 16 + c) * K + k0;
      bf16x8 b = mk_frag(wp, wp + 16);
      acc[nt] = __builtin_amdgcn_mfma_f32_16x16x32_bf16(a, b, acc[nt], 0, 0, 0);
    }
  }
}

// bias add + LayerNorm + ReLU + store bf16 to swizzled LDS (stride 512B)
__device__ __forceinline__ void ln_relu_store(f32x4* acc,
    const float* __restrict__ bias, const float* __restrict__ gam,
    const float* __restrict__ bet, void* out0, int c, int q) {
  float s[4] = {0, 0, 0, 0}, ss[4] = {0, 0, 0, 0};
#pragma unroll
  for (int nt = 0; nt < 16; ++nt) {
    float bb = bias[nt * 16 + c];
#pragma unroll
    for (int r = 0; r < 4; ++r) {
      float v = acc[nt][r] + bb;
      acc[nt][r] = v;
      s[r] += v; ss[r] += v * v;
    }
  }
#pragma unroll
  for (int m = 1; m < 16; m <<= 1) {
#pragma unroll
    for (int r = 0; r < 4; ++r) {
      s[r]  += __shfl_xor(s[r],  m, 64);
      ss[r] += __shfl_xor(ss[r], m, 64);
    }
  }
  float mean[4], rs[4];
#pragma unroll
  for (int r = 0; r < 4; ++r) {
    mean[r] = s[r] * (1.f / 256.f);
    float var = ss[r] * (1.f / 256.f) - mean[r] * mean[r];
    rs[r] = rsqrtf(var + 1e-5f);
  }
#pragma unroll
  for (int nt = 0; nt < 16; ++nt) {
    float gg = gam[nt * 16 + c], bb = bet[nt * 16 + c];
#pragma unroll
    for (int r = 0; r < 4; ++r) {
      float v = (acc[nt][r] - mean[r]) * rs[r] * gg + bb;
      v = fmaxf(v, 0.f);
      *(__hip_bfloat16*)lds_at(out0, q * 4 + r, (nt * 16 + c) * 2, 512) =
          __float2bfloat16(v);
    }
  }
}

// load 16 rows x 64 cols fp32 -> bf16 swizzled LDS [16][64] (stride 128B)
__device__ __forceinline__ void load_x(const float* __restrict__ src, void* W, int lane) {
  const int row = lane >> 2, cb = (lane & 3) * 16;
#pragma unroll
  for (int i = 0; i < 4; ++i) {
    float4 v = *reinterpret_cast<const float4*>(src + row * 64 + cb + i * 4);
    __hip_bfloat16 h[4] = {__float2bfloat16(v.x), __float2bfloat16(v.y),
                           __float2bfloat16(v.z), __float2bfloat16(v.w)};
    *(unsigned long long*)lds_at(W, row, (cb + i * 4) * 2, 128) =
        *reinterpret_cast<unsigned long long*>(h);
  }
}

__device__ __forceinline__ void softmax_write(f32x4* acc3,
    const float* __restrict__ ab3, float* __restrict__ out,
    int grow0, int c, int q) {
  float b0 = ab3[c];
  float b1 = (c < 2) ? ab3[16 + c] : 0.f;
#pragma unroll
  for (int r = 0; r < 4; ++r) {
    float x0 = acc3[0][r] + b0;
    float x1 = (c < 2) ? (acc3[1][r] + b1) : -1e30f;
    float mx = fmaxf(x0, x1);
#pragma unroll
    for (int m = 1; m < 16; m <<= 1) mx = fmaxf(mx, __shfl_xor(mx, m, 64));
    float e0 = __expf(x0 - mx);
    float e1 = (c < 2) ? __expf(x1 - mx) : 0.f;
    float sm = e0 + e1;
#pragma unroll
    for (int m = 1; m < 16; m <<= 1) sm += __shfl_xor(sm, m, 64);
    float inv = 1.f / sm;
    int gr = grow0 + q * 4 + r;
    out[gr * 20 + c] = e0 * inv;
    if (c < 2) out[gr * 20 + 16 + c] = e1 * inv;
  }
}

// ---------------------------------------------------------------------------
__global__ void prep_weights(const float* __restrict__ aw1, const float* __restrict__ aw2,
                             const float* __restrict__ aw3, const float* __restrict__ cw1,
                             const float* __restrict__ cw2, const float* __restrict__ cw3,
                             __hip_bfloat16* __restrict__ wb) {
  int i = blockIdx.x * 256 + threadIdx.x;
  if (i >= W_ELEMS) return;
  float v;
  if (i < OFF_AW2T)      { int j = i;            int n = j >> 6, k = j & 63;  v = aw1[k * 256 + n]; }
  else if (i < OFF_AW3T) { int j = i - OFF_AW2T; int n = j >> 8, k = j & 255; v = aw2[k * 256 + n]; }
  else if (i < OFF_CW1T) { int j = i - OFF_AW3T; int n = j >> 8, k = j & 255; v = (n < 18) ? aw3[k * 18 + n] : 0.f; }
  else if (i < OFF_CW2T) { int j = i - OFF_CW1T; int n = j >> 6, k = j & 63;  v = cw1[k * 256 + n]; }
  else if (i < OFF_CW3T) { int j = i - OFF_CW2T; int n = j >> 8, k = j & 255; v = cw2[k * 256 + n]; }
  else                   { int j = i - OFF_CW3T; int n = j >> 8, k = j & 255; v = (n == 0) ? cw3[k] : 0.f; }
  wb[i] = __float2bfloat16(v);
}

// ---------------------------------------------------------------------------
__global__ __launch_bounds__(256, 2) void mlp_kernel(
    const float* __restrict__ states, const float* __restrict__ next_states,
    const float* __restrict__ rewards, const float* __restrict__ masks,
    const float* __restrict__ ab1, const float* __restrict__ ag1, const float* __restrict__ an1,
    const float* __restrict__ ab2, const float* __restrict__ ag2, const float* __restrict__ an2,
    const float* __restrict__ ab3,
    const float* __restrict__ cb1, const float* __restrict__ cg1, const float* __restrict__ cn1,
    const float* __restrict__ cb2, const float* __restrict__ cg2, const float* __restrict__ cn2,
    const float* __restrict__ cb3,
    const __hip_bfloat16* __restrict__ wbuf,
    float* __restrict__ deltas, float* __restrict__ out) {
  __shared__ __hip_bfloat16 smem[4][16 * 256];   // 8 KB per wave, waves independent
  const int tid = threadIdx.x;
  const int wave = tid >> 6, lane = tid & 63;
  const int c = lane & 15, q = lane >> 4;
  void* W = (void*)smem[wave];
  const int grow0 = blockIdx.x * 64 + wave * 16;

  f32x4 acc[16];

  // ---- ACTOR on states ----
  load_x(states + (size_t)grow0 * 64, W, lane);
  run_gemm<64, 16>(W, 128, wbuf + OFF_AW1T, c, q, acc);
  ln_relu_store(acc, ab1, ag1, an1, W, c, q);
  run_gemm<256, 16>(W, 512, wbuf + OFF_AW2T, c, q, acc);
  ln_relu_store(acc, ab2, ag2, an2, W, c, q);
  {
    f32x4 acc3[2];
    run_gemm<256, 2>(W, 512, wbuf + OFF_AW3T, c, q, acc3);
    softmax_write(acc3, ab3, out, grow0, c, q);
  }

  // ---- CRITIC on states ----
  load_x(states + (size_t)grow0 * 64, W, lane);
  run_gemm<64, 16>(W, 128, wbuf + OFF_CW1T, c, q, acc);
  ln_relu_store(acc, cb1, cg1, cn1, W, c, q);
  run_gemm<256, 16>(W, 512, wbuf + OFF_CW2T, c, q, acc);
  ln_relu_store(acc, cb2, cg2, cn2, W, c, q);
  float vstate[4];
  {
    f32x4 accv[1];
    run_gemm<256, 1>(W, 512, wbuf + OFF_CW3T, c, q, accv);
    float b3 = cb3[0];
#pragma unroll
    for (int r = 0; r < 4; ++r) vstate[r] = accv[0][r] + b3;
    if (c == 0) {
#pragma unroll
      for (int r = 0; r < 4; ++r) out[(grow0 + q * 4 + r) * 20 + 19] = vstate[r];
    }
  }

  // ---- CRITIC on next_states ----
  load_x(next_states + (size_t)grow0 * 64, W, lane);
  run_gemm<64, 16>(W, 128, wbuf + OFF_CW1T, c, q, acc);
  ln_relu_store(acc, cb1, cg1, cn1, W, c, q);
  run_gemm<256, 16>(W, 512, wbuf + OFF_CW2T, c, q, acc);
  ln_relu_store(acc, cb2, cg2, cn2, W, c, q);
  {
    f32x4 accv[1];
    run_gemm<256, 1>(W, 512, wbuf + OFF_CW3T, c, q, accv);
    float b3 = cb3[0];
    if (c == 0) {
#pragma unroll
      for (int r = 0; r < 4; ++r) {
        int gr = grow0 + q * 4 + r;
        float nv = accv[0][r] + b3;
        deltas[gr] = rewards[gr] + 0.99f * nv * masks[gr] - vstate[r];
      }
    }
  }
}

// ---------------------------------------------------------------------------
// GAE: adv[i] = delta[i] + GL*mask[i]*adv[i+1].  Chunk-parallel with 512
// lookahead (GL^512 ~ 4e-13 -> truncation negligible). values were stashed at
// out[:,19]; overwrite with returns, adv at out[:,18].
__global__ void gae_kernel(const float* __restrict__ deltas,
                           const float* __restrict__ masks,
                           float* __restrict__ out) {
  const int t = blockIdx.x * blockDim.x + threadIdx.x;  // 0..1023
  const int s = t * 512;
  int e = s + 1024;
  if (e > T_SZ) e = T_SZ;
  float g = 0.f;
  int j = e - 1;
  for (; j >= s + 512; --j) g = deltas[j] + (GL * masks[j]) * g;
  for (; j >= s; --j) {
    g = deltas[j] + (GL * masks[j]) * g;
    float val = out[j * 20 + 19];
    out[j * 20 + 18] = g;
    out[j * 20 + 19] = g + val;
  }
}

// ---------------------------------------------------------------------------
extern "C" void kernel_launch(void* const* d_in, const int* in_sizes, int n_in,
                              void* d_out, int out_size, void* d_ws, size_t ws_size,
                              hipStream_t stream) {
  const float* states      = (const float*)d_in[0];
  const float* next_states = (const float*)d_in[1];
  const float* rewards     = (const float*)d_in[2];
  const float* masks       = (const float*)d_in[3];
  const float* aw1 = (const float*)d_in[4];
  const float* ab1 = (const float*)d_in[5];
  const float* ag1 = (const float*)d_in[6];
  const float* an1 = (const float*)d_in[7];
  const float* aw2 = (const float*)d_in[8];
  const float* ab2 = (const float*)d_in[9];
  const float* ag2 = (const float*)d_in[10];
  const float* an2 = (const float*)d_in[11];
  const float* aw3 = (const float*)d_in[12];
  const float* ab3 = (const float*)d_in[13];
  const float* cw1 = (const float*)d_in[14];
  const float* cb1 = (const float*)d_in[15];
  const float* cg1 = (const float*)d_in[16];
  const float* cn1 = (const float*)d_in[17];
  const float* cw2 = (const float*)d_in[18];
  const float* cb2 = (const float*)d_in[19];
  const float* cg2 = (const float*)d_in[20];
  const float* cn2 = (const float*)d_in[21];
  const float* cw3 = (const float*)d_in[22];
  const float* cb3 = (const float*)d_in[23];

  __hip_bfloat16* wbuf = (__hip_bfloat16*)d_ws;
  float* deltas = (float*)((char*)d_ws + OFF_DELTAS_BYTES);
  float* out = (float*)d_out;

  prep_weights<<<(W_ELEMS + 255) / 256, 256, 0, stream>>>(aw1, aw2, aw3, cw1, cw2, cw3, wbuf);
  mlp_kernel<<<T_SZ / 64, 256, 0, stream>>>(
      states, next_states, rewards, masks,
      ab1, ag1, an1, ab2, ag2, an2, ab3,
      cb1, cg1, cn1, cb2, cg2, cn2, cb3,
      wbuf, deltas, out);
  gae_kernel<<<4, 256, 0, stream>>>(deltas, masks, out);
}

// Round 2
// 5854.985 us; speedup vs baseline: 1.0586x; 1.0586x over previous
//
#include <hip/hip_runtime.h>
#include <hip/hip_bf16.h>

// ============================================================================
// PPO agent fused forward (round 2):
//  - Fix: round-1 spilled acc[] to scratch (4 GB scratch writes/dispatch).
//    Pin 2 waves/EU -> 256 VGPR budget, restructure to ~200 VGPRs.
//  - A-pairing: each wave owns 32 timesteps; every weight stream (B) serves
//    two A-tiles (actor: rows 0-15/16-31; critic: states/next_states), halving
//    B traffic to ~8.4 GB (L2-resident).
//  - k-permuted layout: fragment = one 16B load. perm within each 32-k panel:
//    pos = (q*8 + h*4 + j) for k = q*4 + h*16 + j  -> A and B both permuted,
//    MFMA k-sum invariant.
// ============================================================================

#define T_SZ 524288
#define GL 0.9405f   // GAMMA*LAM

typedef __attribute__((ext_vector_type(8))) short bf16x8;   // 8 bf16 (4 VGPRs)
typedef __attribute__((ext_vector_type(4))) float f32x4;

// ws layout (bf16 elements); weights stored [N][K], k-permuted
#define OFF_AW1T 0        // [256][64]
#define OFF_AW2T 16384    // [256][256]
#define OFF_AW3T 81920    // [32][256]  rows >=18 zero
#define OFF_CW1T 90112    // [256][64]
#define OFF_CW2T 106496   // [256][256]
#define OFF_CW3T 172032   // [16][256]  rows >=1 zero
#define W_ELEMS  176128
#define OFF_DELTAS_BYTES 352256

// k-permutation within a 32-wide panel: k = p*32 + h*16 + q*4 + j
//   -> pos = p*32 + q*8 + h*4 + j   (so lane q's 8 bf16 are contiguous 16B)
__device__ __forceinline__ int perm_k(int k) {
  int p = k >> 5, w = k & 31;
  return (p << 5) | (((w & 15) >> 2) << 3) | ((w >> 4) << 2) | (w & 3);
}

// 16B-granular XOR swizzle: rows at stride 128/512B spread across banks
__device__ __forceinline__ void* lds_at(void* base, int row, int colByte, int strideB) {
  return (char*)base + row * strideB + (colByte ^ ((row & 7) << 4));
}

// ---------------------------------------------------------------------------
// Paired GEMM: one B stream (global, [N][K] k-permuted bf16) feeds two A tiles
// (LDS, k-permuted, swizzled). acc[nt] = D(row=q*4+reg, col=nt*16+c).
template<int K, int NT>
__device__ __forceinline__ void gemm_pair(const void* A0, const void* A1, int astrB,
                                          const __hip_bfloat16* __restrict__ Wt,
                                          int c, int q, f32x4* acc0, f32x4* acc1) {
#pragma unroll
  for (int nt = 0; nt < NT; ++nt) {
    acc0[nt] = (f32x4){0.f, 0.f, 0.f, 0.f};
    acc1[nt] = (f32x4){0.f, 0.f, 0.f, 0.f};
  }
#pragma unroll
  for (int ks = 0; ks < K / 32; ++ks) {
    const int cb = ks * 64 + q * 16;
    bf16x8 a0 = *(const bf16x8*)lds_at((void*)A0, c, cb, astrB);
    bf16x8 a1 = *(const bf16x8*)lds_at((void*)A1, c, cb, astrB);
#pragma unroll
    for (int nt = 0; nt < NT; ++nt) {
      bf16x8 b = *(const bf16x8*)(Wt + (size_t)(nt * 16 + c) * K + ks * 32 + q * 8);
      acc0[nt] = __builtin_amdgcn_mfma_f32_16x16x32_bf16(a0, b, acc0[nt], 0, 0, 0);
      acc1[nt] = __builtin_amdgcn_mfma_f32_16x16x32_bf16(a1, b, acc1[nt], 0, 0, 0);
    }
  }
}

// bias + LayerNorm + ReLU + store bf16 (k-permuted, swizzled) to LDS stride 512B
__device__ __forceinline__ void ln_relu_store(f32x4* acc,
    const float* __restrict__ bias, const float* __restrict__ gam,
    const float* __restrict__ bet, void* out0, int c, int q) {
  float s[4] = {0, 0, 0, 0}, ss[4] = {0, 0, 0, 0};
#pragma unroll
  for (int nt = 0; nt < 16; ++nt) {
    float bb = bias[nt * 16 + c];
#pragma unroll
    for (int r = 0; r < 4; ++r) {
      float v = acc[nt][r] + bb;
      acc[nt][r] = v;
      s[r] += v; ss[r] += v * v;
    }
  }
#pragma unroll
  for (int m = 1; m < 16; m <<= 1) {
#pragma unroll
    for (int r = 0; r < 4; ++r) {
      s[r]  += __shfl_xor(s[r],  m, 64);
      ss[r] += __shfl_xor(ss[r], m, 64);
    }
  }
  float mean[4], rs[4];
#pragma unroll
  for (int r = 0; r < 4; ++r) {
    mean[r] = s[r] * (1.f / 256.f);
    float var = ss[r] * (1.f / 256.f) - mean[r] * mean[r];
    rs[r] = rsqrtf(var + 1e-5f);
  }
  const int cbase = ((c >> 2) << 3) + (c & 3);
#pragma unroll
  for (int nt = 0; nt < 16; ++nt) {
    float gg = gam[nt * 16 + c], bb = bet[nt * 16 + c];
    const int pos = ((nt >> 1) << 5) + ((nt & 1) << 2) + cbase;  // perm_k(nt*16+c)
#pragma unroll
    for (int r = 0; r < 4; ++r) {
      float v = (acc[nt][r] - mean[r]) * rs[r] * gg + bb;
      v = fmaxf(v, 0.f);
      *(__hip_bfloat16*)lds_at(out0, q * 4 + r, pos * 2, 512) = __float2bfloat16(v);
    }
  }
}

// load 16 rows x 64 cols fp32 -> bf16 k-permuted swizzled LDS [16][64] (stride 128B)
__device__ __forceinline__ void load_x(const float* __restrict__ src, void* W, int lane) {
  const int row = lane >> 2, cg = (lane & 3) * 16;
#pragma unroll
  for (int i = 0; i < 4; ++i) {
    const int k0 = cg + i * 4;
    float4 v = *reinterpret_cast<const float4*>(src + (size_t)row * 64 + k0);
    __hip_bfloat16 h[4] = {__float2bfloat16(v.x), __float2bfloat16(v.y),
                           __float2bfloat16(v.z), __float2bfloat16(v.w)};
    *(unsigned long long*)lds_at(W, row, perm_k(k0) * 2, 128) =
        *reinterpret_cast<unsigned long long*>(h);
  }
}

__device__ __forceinline__ void softmax_write(f32x4* acc3,
    const float* __restrict__ ab3, float* __restrict__ out,
    int grow0, int c, int q) {
  float b0 = ab3[c];
  float b1 = (c < 2) ? ab3[16 + c] : 0.f;
#pragma unroll
  for (int r = 0; r < 4; ++r) {
    float x0 = acc3[0][r] + b0;
    float x1 = (c < 2) ? (acc3[1][r] + b1) : -1e30f;
    float mx = fmaxf(x0, x1);
#pragma unroll
    for (int m = 1; m < 16; m <<= 1) mx = fmaxf(mx, __shfl_xor(mx, m, 64));
    float e0 = __expf(x0 - mx);
    float e1 = (c < 2) ? __expf(x1 - mx) : 0.f;
    float sm = e0 + e1;
#pragma unroll
    for (int m = 1; m < 16; m <<= 1) sm += __shfl_xor(sm, m, 64);
    float inv = 1.f / sm;
    int gr = grow0 + q * 4 + r;
    out[(size_t)gr * 20 + c] = e0 * inv;
    if (c < 2) out[(size_t)gr * 20 + 16 + c] = e1 * inv;
  }
}

// ---------------------------------------------------------------------------
__global__ void prep_weights(const float* __restrict__ aw1, const float* __restrict__ aw2,
                             const float* __restrict__ aw3, const float* __restrict__ cw1,
                             const float* __restrict__ cw2, const float* __restrict__ cw3,
                             __hip_bfloat16* __restrict__ wb) {
  int i = blockIdx.x * 256 + threadIdx.x;
  if (i >= W_ELEMS) return;
  float v; int dst;
  if (i < OFF_AW2T)      { int j = i;            int n = j >> 6, k = j & 63;  v = aw1[k * 256 + n];              dst = OFF_AW1T + n * 64  + perm_k(k); }
  else if (i < OFF_AW3T) { int j = i - OFF_AW2T; int n = j >> 8, k = j & 255; v = aw2[k * 256 + n];              dst = OFF_AW2T + n * 256 + perm_k(k); }
  else if (i < OFF_CW1T) { int j = i - OFF_AW3T; int n = j >> 8, k = j & 255; v = (n < 18) ? aw3[k * 18 + n] : 0.f; dst = OFF_AW3T + n * 256 + perm_k(k); }
  else if (i < OFF_CW2T) { int j = i - OFF_CW1T; int n = j >> 6, k = j & 63;  v = cw1[k * 256 + n];              dst = OFF_CW1T + n * 64  + perm_k(k); }
  else if (i < OFF_CW3T) { int j = i - OFF_CW2T; int n = j >> 8, k = j & 255; v = cw2[k * 256 + n];              dst = OFF_CW2T + n * 256 + perm_k(k); }
  else                   { int j = i - OFF_CW3T; int n = j >> 8, k = j & 255; v = (n == 0) ? cw3[k] : 0.f;       dst = OFF_CW3T + n * 256 + perm_k(k); }
  wb[dst] = __float2bfloat16(v);
}

// ---------------------------------------------------------------------------
__global__ __launch_bounds__(256)
__attribute__((amdgpu_waves_per_eu(2, 2)))
void mlp_kernel(
    const float* __restrict__ states, const float* __restrict__ next_states,
    const float* __restrict__ rewards, const float* __restrict__ masks,
    const float* __restrict__ ab1, const float* __restrict__ ag1, const float* __restrict__ an1,
    const float* __restrict__ ab2, const float* __restrict__ ag2, const float* __restrict__ an2,
    const float* __restrict__ ab3,
    const float* __restrict__ cb1, const float* __restrict__ cg1, const float* __restrict__ cn1,
    const float* __restrict__ cb2, const float* __restrict__ cg2, const float* __restrict__ cn2,
    const float* __restrict__ cb3,
    const __hip_bfloat16* __restrict__ wbuf,
    float* __restrict__ deltas, float* __restrict__ out) {
  __shared__ char smem[4][2][8192];   // 2 tile buffers per wave, waves independent
  const int tid = threadIdx.x;
  const int wave = tid >> 6, lane = tid & 63;
  const int c = lane & 15, q = lane >> 4;
  void* B0 = (void*)smem[wave][0];
  void* B1 = (void*)smem[wave][1];
  const int base = blockIdx.x * 128 + wave * 32;   // 32 timesteps per wave

  f32x4 acc0[16], acc1[16];

  // ---- ACTOR rows [base, base+32) : two A-tiles share the B stream ----
  load_x(states + (size_t)base * 64, B0, lane);
  load_x(states + (size_t)(base + 16) * 64, B1, lane);
  gemm_pair<64, 16>(B0, B1, 128, wbuf + OFF_AW1T, c, q, acc0, acc1);
  ln_relu_store(acc0, ab1, ag1, an1, B0, c, q);
  ln_relu_store(acc1, ab1, ag1, an1, B1, c, q);
  gemm_pair<256, 16>(B0, B1, 512, wbuf + OFF_AW2T, c, q, acc0, acc1);
  ln_relu_store(acc0, ab2, ag2, an2, B0, c, q);
  ln_relu_store(acc1, ab2, ag2, an2, B1, c, q);
  {
    f32x4 p0[2], p1[2];
    gemm_pair<256, 2>(B0, B1, 512, wbuf + OFF_AW3T, c, q, p0, p1);
    softmax_write(p0, ab3, out, base, c, q);
    softmax_write(p1, ab3, out, base + 16, c, q);
  }

  // ---- CRITIC: states (B0) paired with next_states (B1), 2 passes ----
#pragma unroll 1
  for (int p = 0; p < 2; ++p) {
    const int rb = base + p * 16;
    load_x(states + (size_t)rb * 64, B0, lane);
    load_x(next_states + (size_t)rb * 64, B1, lane);
    gemm_pair<64, 16>(B0, B1, 128, wbuf + OFF_CW1T, c, q, acc0, acc1);
    ln_relu_store(acc0, cb1, cg1, cn1, B0, c, q);
    ln_relu_store(acc1, cb1, cg1, cn1, B1, c, q);
    gemm_pair<256, 16>(B0, B1, 512, wbuf + OFF_CW2T, c, q, acc0, acc1);
    ln_relu_store(acc0, cb2, cg2, cn2, B0, c, q);
    ln_relu_store(acc1, cb2, cg2, cn2, B1, c, q);
    {
      f32x4 v0[1], v1[1];
      gemm_pair<256, 1>(B0, B1, 512, wbuf + OFF_CW3T, c, q, v0, v1);
      const float b3 = cb3[0];
      if (c == 0) {
#pragma unroll
        for (int r = 0; r < 4; ++r) {
          const int gr = rb + q * 4 + r;
          const float v  = v0[0][r] + b3;
          const float nv = v1[0][r] + b3;
          out[(size_t)gr * 20 + 19] = v;   // stash value; gae turns it into return
          deltas[gr] = rewards[gr] + 0.99f * nv * masks[gr] - v;
        }
      }
    }
  }
}

// ---------------------------------------------------------------------------
// GAE: adv[i] = delta[i] + GL*mask[i]*adv[i+1]; chunk-parallel, 512 lookahead
// (GL^512 ~ 4e-13). value stashed at out[:,19] -> returns; adv at out[:,18].
__global__ void gae_kernel(const float* __restrict__ deltas,
                           const float* __restrict__ masks,
                           float* __restrict__ out) {
  const int t = blockIdx.x * blockDim.x + threadIdx.x;  // 0..1023
  const int s = t * 512;
  int e = s + 1024;
  if (e > T_SZ) e = T_SZ;
  float g = 0.f;
  int j = e - 1;
  for (; j >= s + 512; --j) g = deltas[j] + (GL * masks[j]) * g;
  for (; j >= s; --j) {
    g = deltas[j] + (GL * masks[j]) * g;
    float val = out[(size_t)j * 20 + 19];
    out[(size_t)j * 20 + 18] = g;
    out[(size_t)j * 20 + 19] = g + val;
  }
}

// ---------------------------------------------------------------------------
extern "C" void kernel_launch(void* const* d_in, const int* in_sizes, int n_in,
                              void* d_out, int out_size, void* d_ws, size_t ws_size,
                              hipStream_t stream) {
  const float* states      = (const float*)d_in[0];
  const float* next_states = (const float*)d_in[1];
  const float* rewards     = (const float*)d_in[2];
  const float* masks       = (const float*)d_in[3];
  const float* aw1 = (const float*)d_in[4];
  const float* ab1 = (const float*)d_in[5];
  const float* ag1 = (const float*)d_in[6];
  const float* an1 = (const float*)d_in[7];
  const float* aw2 = (const float*)d_in[8];
  const float* ab2 = (const float*)d_in[9];
  const float* ag2 = (const float*)d_in[10];
  const float* an2 = (const float*)d_in[11];
  const float* aw3 = (const float*)d_in[12];
  const float* ab3 = (const float*)d_in[13];
  const float* cw1 = (const float*)d_in[14];
  const float* cb1 = (const float*)d_in[15];
  const float* cg1 = (const float*)d_in[16];
  const float* cn1 = (const float*)d_in[17];
  const float* cw2 = (const float*)d_in[18];
  const float* cb2 = (const float*)d_in[19];
  const float* cg2 = (const float*)d_in[20];
  const float* cn2 = (const float*)d_in[21];
  const float* cw3 = (const float*)d_in[22];
  const float* cb3 = (const float*)d_in[23];

  __hip_bfloat16* wbuf = (__hip_bfloat16*)d_ws;
  float* deltas = (float*)((char*)d_ws + OFF_DELTAS_BYTES);
  float* out = (float*)d_out;

  prep_weights<<<(W_ELEMS + 255) / 256, 256, 0, stream>>>(aw1, aw2, aw3, cw1, cw2, cw3, wbuf);
  mlp_kernel<<<T_SZ / 128, 256, 0, stream>>>(
      states, next_states, rewards, masks,
      ab1, ag1, an1, ab2, ag2, an2, ab3,
      cb1, cg1, cn1, cb2, cg2, cn2, cb3,
      wbuf, deltas, out);
  gae_kernel<<<4, 256, 0, stream>>>(deltas, masks, out);
}

// Round 3
// 3904.288 us; speedup vs baseline: 1.5875x; 1.4996x over previous
//
#include <hip/hip_runtime.h>
#include <hip/hip_bf16.h>

// ============================================================================
// PPO agent fused forward (round 3):
//  Root cause rounds 1-2: allocator pins 128 VGPRs; paired design needed >200
//  -> catastrophic scratch spill (10 GB/dispatch). Fix: design UNDER 128.
//   - one 16-row tile per wave, acc[16] = 64 VGPRs, ~115 total demand
//   - single in-place 8KB LDS buffer/wave (per-wave DS ops are in-order),
//     32KB/block -> 4 blocks/CU, 4 waves/SIMD
//   - __syncthreads between phases: scheduler fence + waves lockstep so the
//     identical per-wave weight streams hit L1 (B-reuse x4)
//   - sched_barrier(0) every 4 MFMAs caps b-prefetch window (~16 VGPRs)
//   - k-perm pos = p*32 + (k&15)*2 + h: LN stores 2 cols per b32 (32 stores),
//     load_x writes 2xb128; A and B share the perm -> MFMA k-sum invariant
// ============================================================================

#define T_SZ 524288
#define GL 0.9405f   // GAMMA*LAM

typedef __attribute__((ext_vector_type(8))) short bf16x8;   // 8 bf16 (4 VGPRs)
typedef __attribute__((ext_vector_type(4))) float f32x4;

// ws layout (bf16 elements); weights stored [N][K], k-permuted
#define OFF_AW1T 0        // [256][64]
#define OFF_AW2T 16384    // [256][256]
#define OFF_AW3T 81920    // [32][256]  rows >=18 zero
#define OFF_CW1T 90112    // [256][64]
#define OFF_CW2T 106496   // [256][256]
#define OFF_CW3T 172032   // [16][256]  rows >=1 zero
#define W_ELEMS  176128
#define OFF_DELTAS_BYTES 352256

// k = p*32 + h*16 + w (w=k&15, h=(k>>4)&1) -> pos = p*32 + w*2 + h
__device__ __forceinline__ int perm_k(int k) {
  return (k & ~31) | ((k & 15) << 1) | ((k >> 4) & 1);
}

// 16B-granular XOR swizzle
__device__ __forceinline__ void* lds_at(void* base, int row, int colByte, int strideB) {
  return (char*)base + row * strideB + (colByte ^ ((row & 7) << 4));
}

__device__ __forceinline__ unsigned pack2(float a, float b) {
  union { __hip_bfloat16 h; unsigned short u; } ua, ub;
  ua.h = __float2bfloat16(a); ub.h = __float2bfloat16(b);
  return (unsigned)ua.u | ((unsigned)ub.u << 16);
}

// ---------------------------------------------------------------------------
// GEMM: A from swizzled k-permuted LDS (rows = c), B from global [N][K]
// k-permuted bf16. acc[nt] = D(row=q*4+reg, col=nt*16+c).
template<int K, int NT>
__device__ __forceinline__ void run_gemm(void* A0, int astrB,
                                         const __hip_bfloat16* __restrict__ Wt,
                                         int c, int q, f32x4* acc) {
#pragma unroll
  for (int nt = 0; nt < NT; ++nt) acc[nt] = (f32x4){0.f, 0.f, 0.f, 0.f};
#pragma unroll
  for (int ks = 0; ks < K / 32; ++ks) {
    bf16x8 a = *(const bf16x8*)lds_at(A0, c, ks * 64 + q * 16, astrB);
    const __hip_bfloat16* wp = Wt + (size_t)c * K + ks * 32 + q * 8;
#pragma unroll
    for (int nt = 0; nt < NT; ++nt) {
      bf16x8 b = *(const bf16x8*)(wp + (size_t)nt * 16 * K);
      acc[nt] = __builtin_amdgcn_mfma_f32_16x16x32_bf16(a, b, acc[nt], 0, 0, 0);
      if ((nt & 3) == 3) __builtin_amdgcn_sched_barrier(0);  // cap b window
    }
  }
}

// bias + LayerNorm + ReLU + store bf16 pairs (b32) to k-permuted swizzled LDS
__device__ __forceinline__ void ln_relu_store(f32x4* acc,
    const float* __restrict__ bias, const float* __restrict__ gam,
    const float* __restrict__ bet, void* out0, int c, int q) {
  float s[4] = {0, 0, 0, 0}, ss[4] = {0, 0, 0, 0};
#pragma unroll
  for (int nt = 0; nt < 16; ++nt) {
    float bb = bias[nt * 16 + c];
#pragma unroll
    for (int r = 0; r < 4; ++r) {
      float v = acc[nt][r] + bb;
      acc[nt][r] = v;
      s[r] += v; ss[r] += v * v;
    }
  }
#pragma unroll
  for (int m = 1; m < 16; m <<= 1) {
#pragma unroll
    for (int r = 0; r < 4; ++r) {
      s[r]  += __shfl_xor(s[r],  m, 64);
      ss[r] += __shfl_xor(ss[r], m, 64);
    }
  }
  float mean[4], rs[4];
#pragma unroll
  for (int r = 0; r < 4; ++r) {
    mean[r] = s[r] * (1.f / 256.f);
    float var = ss[r] * (1.f / 256.f) - mean[r] * mean[r];
    rs[r] = rsqrtf(var + 1e-5f);
  }
#pragma unroll
  for (int p = 0; p < 8; ++p) {
    const float g0 = gam[(2 * p) * 16 + c],     b0 = bet[(2 * p) * 16 + c];
    const float g1 = gam[(2 * p + 1) * 16 + c], b1 = bet[(2 * p + 1) * 16 + c];
#pragma unroll
    for (int r = 0; r < 4; ++r) {
      float v0 = fmaxf((acc[2 * p][r]     - mean[r]) * rs[r] * g0 + b0, 0.f);
      float v1 = fmaxf((acc[2 * p + 1][r] - mean[r]) * rs[r] * g1 + b1, 0.f);
      *(unsigned*)lds_at(out0, q * 4 + r, p * 64 + c * 4, 512) = pack2(v0, v1);
    }
  }
}

// load 16 rows x 64 cols fp32 -> bf16 k-permuted swizzled LDS [16][.] stride 128B
__device__ __forceinline__ void load_x(const float* __restrict__ src, void* W, int lane) {
  const int row = lane >> 2, m = lane & 3;
  const int p = m >> 1, half = m & 1;
  const int kb = p * 32 + half * 8;
  const float* rp = src + (size_t)row * 64;
  float4 x0a = *(const float4*)(rp + kb);
  float4 x0b = *(const float4*)(rp + kb + 4);
  float4 x1a = *(const float4*)(rp + kb + 16);
  float4 x1b = *(const float4*)(rp + kb + 20);
  unsigned u[8];
  u[0] = pack2(x0a.x, x1a.x); u[1] = pack2(x0a.y, x1a.y);
  u[2] = pack2(x0a.z, x1a.z); u[3] = pack2(x0a.w, x1a.w);
  u[4] = pack2(x0b.x, x1b.x); u[5] = pack2(x0b.y, x1b.y);
  u[6] = pack2(x0b.z, x1b.z); u[7] = pack2(x0b.w, x1b.w);
  const int byte0 = p * 64 + half * 32;
  *(uint4*)lds_at(W, row, byte0, 128)      = *(uint4*)(u);
  *(uint4*)lds_at(W, row, byte0 + 16, 128) = *(uint4*)(u + 4);
}

__device__ __forceinline__ void softmax_write(f32x4* acc3,
    const float* __restrict__ ab3, float* __restrict__ out,
    int grow0, int c, int q) {
  float b0 = ab3[c];
  float b1 = (c < 2) ? ab3[16 + c] : 0.f;
#pragma unroll
  for (int r = 0; r < 4; ++r) {
    float x0 = acc3[0][r] + b0;
    float x1 = (c < 2) ? (acc3[1][r] + b1) : -1e30f;
    float mx = fmaxf(x0, x1);
#pragma unroll
    for (int m = 1; m < 16; m <<= 1) mx = fmaxf(mx, __shfl_xor(mx, m, 64));
    float e0 = __expf(x0 - mx);
    float e1 = (c < 2) ? __expf(x1 - mx) : 0.f;
    float sm = e0 + e1;
#pragma unroll
    for (int m = 1; m < 16; m <<= 1) sm += __shfl_xor(sm, m, 64);
    float inv = 1.f / sm;
    int gr = grow0 + q * 4 + r;
    out[(size_t)gr * 20 + c] = e0 * inv;
    if (c < 2) out[(size_t)gr * 20 + 16 + c] = e1 * inv;
  }
}

// ---------------------------------------------------------------------------
__global__ void prep_weights(const float* __restrict__ aw1, const float* __restrict__ aw2,
                             const float* __restrict__ aw3, const float* __restrict__ cw1,
                             const float* __restrict__ cw2, const float* __restrict__ cw3,
                             __hip_bfloat16* __restrict__ wb) {
  int i = blockIdx.x * 256 + threadIdx.x;
  if (i >= W_ELEMS) return;
  float v; int dst;
  if (i < OFF_AW2T)      { int j = i;            int n = j >> 6, k = j & 63;  v = aw1[k * 256 + n];              dst = OFF_AW1T + n * 64  + perm_k(k); }
  else if (i < OFF_AW3T) { int j = i - OFF_AW2T; int n = j >> 8, k = j & 255; v = aw2[k * 256 + n];              dst = OFF_AW2T + n * 256 + perm_k(k); }
  else if (i < OFF_CW1T) { int j = i - OFF_AW3T; int n = j >> 8, k = j & 255; v = (n < 18) ? aw3[k * 18 + n] : 0.f; dst = OFF_AW3T + n * 256 + perm_k(k); }
  else if (i < OFF_CW2T) { int j = i - OFF_CW1T; int n = j >> 6, k = j & 63;  v = cw1[k * 256 + n];              dst = OFF_CW1T + n * 64  + perm_k(k); }
  else if (i < OFF_CW3T) { int j = i - OFF_CW2T; int n = j >> 8, k = j & 255; v = cw2[k * 256 + n];              dst = OFF_CW2T + n * 256 + perm_k(k); }
  else                   { int j = i - OFF_CW3T; int n = j >> 8, k = j & 255; v = (n == 0) ? cw3[k] : 0.f;       dst = OFF_CW3T + n * 256 + perm_k(k); }
  wb[dst] = __float2bfloat16(v);
}

// ---------------------------------------------------------------------------
__global__ __launch_bounds__(256, 4) void mlp_kernel(
    const float* __restrict__ states, const float* __restrict__ next_states,
    const float* __restrict__ rewards, const float* __restrict__ masks,
    const float* __restrict__ ab1, const float* __restrict__ ag1, const float* __restrict__ an1,
    const float* __restrict__ ab2, const float* __restrict__ ag2, const float* __restrict__ an2,
    const float* __restrict__ ab3,
    const float* __restrict__ cb1, const float* __restrict__ cg1, const float* __restrict__ cn1,
    const float* __restrict__ cb2, const float* __restrict__ cg2, const float* __restrict__ cn2,
    const float* __restrict__ cb3,
    const __hip_bfloat16* __restrict__ wbuf,
    float* __restrict__ deltas, float* __restrict__ out) {
  __shared__ char smem[4][8192];   // single in-place buffer per wave
  const int tid = threadIdx.x;
  const int wave = tid >> 6, lane = tid & 63;
  const int c = lane & 15, q = lane >> 4;
  void* B = (void*)smem[wave];
  const int base = blockIdx.x * 64 + wave * 16;   // 16 timesteps per wave

  f32x4 acc[16];

  // ---- ACTOR(states) ----
  load_x(states + (size_t)base * 64, B, lane);
  __syncthreads();
  run_gemm<64, 16>(B, 128, wbuf + OFF_AW1T, c, q, acc);
  ln_relu_store(acc, ab1, ag1, an1, B, c, q);
  __syncthreads();
  run_gemm<256, 16>(B, 512, wbuf + OFF_AW2T, c, q, acc);
  ln_relu_store(acc, ab2, ag2, an2, B, c, q);
  __syncthreads();
  {
    f32x4 p3[2];
    run_gemm<256, 2>(B, 512, wbuf + OFF_AW3T, c, q, p3);
    softmax_write(p3, ab3, out, base, c, q);
  }
  __syncthreads();

  // ---- CRITIC(states) ----
  load_x(states + (size_t)base * 64, B, lane);
  __syncthreads();
  run_gemm<64, 16>(B, 128, wbuf + OFF_CW1T, c, q, acc);
  ln_relu_store(acc, cb1, cg1, cn1, B, c, q);
  __syncthreads();
  run_gemm<256, 16>(B, 512, wbuf + OFF_CW2T, c, q, acc);
  ln_relu_store(acc, cb2, cg2, cn2, B, c, q);
  __syncthreads();
  float vst[4];
  {
    f32x4 v[1];
    run_gemm<256, 1>(B, 512, wbuf + OFF_CW3T, c, q, v);
    const float b3 = cb3[0];
#pragma unroll
    for (int r = 0; r < 4; ++r) vst[r] = v[0][r] + b3;
  }
  __syncthreads();

  // ---- CRITIC(next_states) ----
  load_x(next_states + (size_t)base * 64, B, lane);
  __syncthreads();
  run_gemm<64, 16>(B, 128, wbuf + OFF_CW1T, c, q, acc);
  ln_relu_store(acc, cb1, cg1, cn1, B, c, q);
  __syncthreads();
  run_gemm<256, 16>(B, 512, wbuf + OFF_CW2T, c, q, acc);
  ln_relu_store(acc, cb2, cg2, cn2, B, c, q);
  __syncthreads();
  {
    f32x4 v[1];
    run_gemm<256, 1>(B, 512, wbuf + OFF_CW3T, c, q, v);
    const float b3 = cb3[0];
    if (c == 0) {
#pragma unroll
      for (int r = 0; r < 4; ++r) {
        const int gr = base + q * 4 + r;
        const float nv = v[0][r] + b3;
        out[(size_t)gr * 20 + 19] = vst[r];   // stash value; gae -> return
        deltas[gr] = rewards[gr] + 0.99f * nv * masks[gr] - vst[r];
      }
    }
  }
}

// ---------------------------------------------------------------------------
// GAE: adv[i] = delta[i] + GL*mask[i]*adv[i+1]; chunk-parallel, 512 lookahead
// (GL^512 ~ 4e-13). value stashed at out[:,19] -> returns; adv at out[:,18].
__global__ void gae_kernel(const float* __restrict__ deltas,
                           const float* __restrict__ masks,
                           float* __restrict__ out) {
  const int t = blockIdx.x * blockDim.x + threadIdx.x;  // 0..1023
  const int s = t * 512;
  int e = s + 1024;
  if (e > T_SZ) e = T_SZ;
  float g = 0.f;
  int j = e - 1;
  for (; j >= s + 512; --j) g = deltas[j] + (GL * masks[j]) * g;
  for (; j >= s; --j) {
    g = deltas[j] + (GL * masks[j]) * g;
    float val = out[(size_t)j * 20 + 19];
    out[(size_t)j * 20 + 18] = g;
    out[(size_t)j * 20 + 19] = g + val;
  }
}

// ---------------------------------------------------------------------------
extern "C" void kernel_launch(void* const* d_in, const int* in_sizes, int n_in,
                              void* d_out, int out_size, void* d_ws, size_t ws_size,
                              hipStream_t stream) {
  const float* states      = (const float*)d_in[0];
  const float* next_states = (const float*)d_in[1];
  const float* rewards     = (const float*)d_in[2];
  const float* masks       = (const float*)d_in[3];
  const float* aw1 = (const float*)d_in[4];
  const float* ab1 = (const float*)d_in[5];
  const float* ag1 = (const float*)d_in[6];
  const float* an1 = (const float*)d_in[7];
  const float* aw2 = (const float*)d_in[8];
  const float* ab2 = (const float*)d_in[9];
  const float* ag2 = (const float*)d_in[10];
  const float* an2 = (const float*)d_in[11];
  const float* aw3 = (const float*)d_in[12];
  const float* ab3 = (const float*)d_in[13];
  const float* cw1 = (const float*)d_in[14];
  const float* cb1 = (const float*)d_in[15];
  const float* cg1 = (const float*)d_in[16];
  const float* cn1 = (const float*)d_in[17];
  const float* cw2 = (const float*)d_in[18];
  const float* cb2 = (const float*)d_in[19];
  const float* cg2 = (const float*)d_in[20];
  const float* cn2 = (const float*)d_in[21];
  const float* cw3 = (const float*)d_in[22];
  const float* cb3 = (const float*)d_in[23];

  __hip_bfloat16* wbuf = (__hip_bfloat16*)d_ws;
  float* deltas = (float*)((char*)d_ws + OFF_DELTAS_BYTES);
  float* out = (float*)d_out;

  prep_weights<<<(W_ELEMS + 255) / 256, 256, 0, stream>>>(aw1, aw2, aw3, cw1, cw2, cw3, wbuf);
  mlp_kernel<<<T_SZ / 64, 256, 0, stream>>>(
      states, next_states, rewards, masks,
      ab1, ag1, an1, ab2, ag2, an2, ab3,
      cb1, cg1, cn1, cb2, cg2, cn2, cb3,
      wbuf, deltas, out);
  gae_kernel<<<4, 256, 0, stream>>>(deltas, masks, out);
}

// Round 4
// 3387.068 us; speedup vs baseline: 1.8299x; 1.1527x over previous
//
#include <hip/hip_runtime.h>
#include <hip/hip_bf16.h>

// ============================================================================
// PPO agent fused forward (round 4):
//  Root cause r1-r3: 64 f32 of persistent accumulator + VALU-heavy LN epilogue
//  touching all of it -> allocator scratch-spills acc (5-10 GB/dispatch).
//  Fix: column-PAIR processing. Per pair: acc0/acc1 (8 VGPRs) -> bias-add,
//  s/ss accumulate, stash pre-LN value bf16-PACKED in 32 u32 regs. After all
//  pairs: shuffle-reduce, unpack/normalize/ReLU/store to LDS (in-place safe:
//  all A-reads precede stores). Worst-case arch pressure ~95 < 128 budget.
//  Also: actor+critic share one load_x(states); gae rewritten wave-parallel
//  (affine suffix scan, coalesced loads) -- r3's serial gae was latency-bound.
// ============================================================================

#define T_SZ 524288
#define GL 0.9405f   // GAMMA*LAM

typedef __attribute__((ext_vector_type(8))) short bf16x8;   // 8 bf16 (4 VGPRs)
typedef __attribute__((ext_vector_type(4))) float f32x4;

// ws layout (bf16 elements); weights stored [N][K], k-permuted
#define OFF_AW1T 0        // [256][64]
#define OFF_AW2T 16384    // [256][256]
#define OFF_AW3T 81920    // [32][256]  rows >=18 zero
#define OFF_CW1T 90112    // [256][64]
#define OFF_CW2T 106496   // [256][256]
#define OFF_CW3T 172032   // [16][256]  rows >=1 zero
#define W_ELEMS  176128
#define OFF_DELTAS_BYTES 352256

// k = p*32 + h*16 + w (w=k&15, h=(k>>4)&1) -> pos = p*32 + w*2 + h
// Applied to BOTH A (LDS) and B (weights) -> MFMA k-sum invariant.
__device__ __forceinline__ int perm_k(int k) {
  return (k & ~31) | ((k & 15) << 1) | ((k >> 4) & 1);
}

// 16B-granular XOR swizzle
__device__ __forceinline__ void* lds_at(void* base, int row, int colByte, int strideB) {
  return (char*)base + row * strideB + (colByte ^ ((row & 7) << 4));
}

__device__ __forceinline__ unsigned pack2(float a, float b) {
  union { __hip_bfloat16 h; unsigned short u; } ua, ub;
  ua.h = __float2bfloat16(a); ub.h = __float2bfloat16(b);
  return (unsigned)ua.u | ((unsigned)ub.u << 16);
}

__device__ __forceinline__ void unpack2(unsigned u, float& a, float& b) {
  union { unsigned u; float f; } x, y;
  x.u = u << 16; y.u = u & 0xFFFF0000u;
  a = x.f; b = y.f;
}

// ---------------------------------------------------------------------------
// Linear(K->256) + bias + LayerNorm + ReLU, column-pair streaming.
// A from LDS (rows=c), B from global [N][K] k-permuted bf16.
// Pre-LN values live bf16-packed in 32 u32 regs; post-LN written to Obuf
// (Obuf may equal Abuf: all A-reads complete before stores).
template<int K>
__device__ __forceinline__ void layer_ln(void* Abuf, int astrB,
    const __hip_bfloat16* __restrict__ Wt,
    const float* __restrict__ bias, const float* __restrict__ gam,
    const float* __restrict__ bet, void* Obuf, int c, int q) {
  float s[4] = {0, 0, 0, 0}, ss[4] = {0, 0, 0, 0};
  unsigned pk[8][4];
#pragma unroll
  for (int p = 0; p < 8; ++p) {
    f32x4 acc0 = {0.f, 0.f, 0.f, 0.f}, acc1 = {0.f, 0.f, 0.f, 0.f};
    const __hip_bfloat16* wp = Wt + ((size_t)(2 * p) * 16 + c) * K + q * 8;
#pragma unroll
    for (int ks = 0; ks < K / 32; ++ks) {
      bf16x8 a = *(const bf16x8*)lds_at(Abuf, c, ks * 64 + q * 16, astrB);
      bf16x8 b0 = *(const bf16x8*)(wp + ks * 32);
      bf16x8 b1 = *(const bf16x8*)(wp + (size_t)16 * K + ks * 32);
      acc0 = __builtin_amdgcn_mfma_f32_16x16x32_bf16(a, b0, acc0, 0, 0, 0);
      acc1 = __builtin_amdgcn_mfma_f32_16x16x32_bf16(a, b1, acc1, 0, 0, 0);
    }
    const float bb0 = bias[2 * p * 16 + c], bb1 = bias[(2 * p + 1) * 16 + c];
#pragma unroll
    for (int r = 0; r < 4; ++r) {
      float v0 = acc0[r] + bb0, v1 = acc1[r] + bb1;
      s[r] += v0 + v1;
      ss[r] += v0 * v0 + v1 * v1;
      pk[p][r] = pack2(v0, v1);
    }
  }
  // row sums over the 16 c-lanes (lane = q*16+c; xor m<16 flips c only)
#pragma unroll
  for (int m = 1; m < 16; m <<= 1) {
#pragma unroll
    for (int r = 0; r < 4; ++r) {
      s[r]  += __shfl_xor(s[r],  m, 64);
      ss[r] += __shfl_xor(ss[r], m, 64);
    }
  }
  float mean[4], rs[4];
#pragma unroll
  for (int r = 0; r < 4; ++r) {
    mean[r] = s[r] * (1.f / 256.f);
    float var = ss[r] * (1.f / 256.f) - mean[r] * mean[r];
    rs[r] = rsqrtf(var + 1e-5f);
  }
#pragma unroll
  for (int p = 0; p < 8; ++p) {
    const float g0 = gam[2 * p * 16 + c],       b0 = bet[2 * p * 16 + c];
    const float g1 = gam[(2 * p + 1) * 16 + c], b1 = bet[(2 * p + 1) * 16 + c];
#pragma unroll
    for (int r = 0; r < 4; ++r) {
      float v0, v1;
      unpack2(pk[p][r], v0, v1);
      float w0 = fmaxf((v0 - mean[r]) * rs[r] * g0 + b0, 0.f);
      float w1 = fmaxf((v1 - mean[r]) * rs[r] * g1 + b1, 0.f);
      *(unsigned*)lds_at(Obuf, q * 4 + r, p * 64 + c * 4, 512) = pack2(w0, w1);
    }
  }
}

// small final GEMM (no LN): NT column-tiles of 16
template<int K, int NT>
__device__ __forceinline__ void run_small(void* Abuf, int astrB,
    const __hip_bfloat16* __restrict__ Wt, int c, int q, f32x4* acc) {
#pragma unroll
  for (int nt = 0; nt < NT; ++nt) acc[nt] = (f32x4){0.f, 0.f, 0.f, 0.f};
#pragma unroll
  for (int ks = 0; ks < K / 32; ++ks) {
    bf16x8 a = *(const bf16x8*)lds_at(Abuf, c, ks * 64 + q * 16, astrB);
#pragma unroll
    for (int nt = 0; nt < NT; ++nt) {
      bf16x8 b = *(const bf16x8*)(Wt + ((size_t)nt * 16 + c) * K + ks * 32 + q * 8);
      acc[nt] = __builtin_amdgcn_mfma_f32_16x16x32_bf16(a, b, acc[nt], 0, 0, 0);
    }
  }
}

// load 16 rows x 64 cols fp32 -> bf16 k-permuted swizzled LDS (stride 128B)
__device__ __forceinline__ void load_x(const float* __restrict__ src, void* W, int lane) {
  const int row = lane >> 2, m = lane & 3;
  const int p = m >> 1, half = m & 1;
  const int kb = p * 32 + half * 8;
  const float* rp = src + (size_t)row * 64;
  float4 x0a = *(const float4*)(rp + kb);
  float4 x0b = *(const float4*)(rp + kb + 4);
  float4 x1a = *(const float4*)(rp + kb + 16);
  float4 x1b = *(const float4*)(rp + kb + 20);
  unsigned u[8];
  u[0] = pack2(x0a.x, x1a.x); u[1] = pack2(x0a.y, x1a.y);
  u[2] = pack2(x0a.z, x1a.z); u[3] = pack2(x0a.w, x1a.w);
  u[4] = pack2(x0b.x, x1b.x); u[5] = pack2(x0b.y, x1b.y);
  u[6] = pack2(x0b.z, x1b.z); u[7] = pack2(x0b.w, x1b.w);
  const int byte0 = p * 64 + half * 32;
  *(uint4*)lds_at(W, row, byte0, 128)      = *(uint4*)(u);
  *(uint4*)lds_at(W, row, byte0 + 16, 128) = *(uint4*)(u + 4);
}

__device__ __forceinline__ void softmax_write(f32x4* acc3,
    const float* __restrict__ ab3, float* __restrict__ out,
    int grow0, int c, int q) {
  float b0 = ab3[c];
  float b1 = (c < 2) ? ab3[16 + c] : 0.f;
#pragma unroll
  for (int r = 0; r < 4; ++r) {
    float x0 = acc3[0][r] + b0;
    float x1 = (c < 2) ? (acc3[1][r] + b1) : -1e30f;
    float mx = fmaxf(x0, x1);
#pragma unroll
    for (int m = 1; m < 16; m <<= 1) mx = fmaxf(mx, __shfl_xor(mx, m, 64));
    float e0 = __expf(x0 - mx);
    float e1 = (c < 2) ? __expf(x1 - mx) : 0.f;
    float sm = e0 + e1;
#pragma unroll
    for (int m = 1; m < 16; m <<= 1) sm += __shfl_xor(sm, m, 64);
    float inv = 1.f / sm;
    int gr = grow0 + q * 4 + r;
    out[(size_t)gr * 20 + c] = e0 * inv;
    if (c < 2) out[(size_t)gr * 20 + 16 + c] = e1 * inv;
  }
}

// ---------------------------------------------------------------------------
__global__ void prep_weights(const float* __restrict__ aw1, const float* __restrict__ aw2,
                             const float* __restrict__ aw3, const float* __restrict__ cw1,
                             const float* __restrict__ cw2, const float* __restrict__ cw3,
                             __hip_bfloat16* __restrict__ wb) {
  int i = blockIdx.x * 256 + threadIdx.x;
  if (i >= W_ELEMS) return;
  float v; int dst;
  if (i < OFF_AW2T)      { int j = i;            int n = j >> 6, k = j & 63;  v = aw1[k * 256 + n];              dst = OFF_AW1T + n * 64  + perm_k(k); }
  else if (i < OFF_AW3T) { int j = i - OFF_AW2T; int n = j >> 8, k = j & 255; v = aw2[k * 256 + n];              dst = OFF_AW2T + n * 256 + perm_k(k); }
  else if (i < OFF_CW1T) { int j = i - OFF_AW3T; int n = j >> 8, k = j & 255; v = (n < 18) ? aw3[k * 18 + n] : 0.f; dst = OFF_AW3T + n * 256 + perm_k(k); }
  else if (i < OFF_CW2T) { int j = i - OFF_CW1T; int n = j >> 6, k = j & 63;  v = cw1[k * 256 + n];              dst = OFF_CW1T + n * 64  + perm_k(k); }
  else if (i < OFF_CW3T) { int j = i - OFF_CW2T; int n = j >> 8, k = j & 255; v = cw2[k * 256 + n];              dst = OFF_CW2T + n * 256 + perm_k(k); }
  else                   { int j = i - OFF_CW3T; int n = j >> 8, k = j & 255; v = (n == 0) ? cw3[k] : 0.f;       dst = OFF_CW3T + n * 256 + perm_k(k); }
  wb[dst] = __float2bfloat16(v);
}

// ---------------------------------------------------------------------------
__global__ __launch_bounds__(256, 4) void mlp_kernel(
    const float* __restrict__ states, const float* __restrict__ next_states,
    const float* __restrict__ rewards, const float* __restrict__ masks,
    const float* __restrict__ ab1, const float* __restrict__ ag1, const float* __restrict__ an1,
    const float* __restrict__ ab2, const float* __restrict__ ag2, const float* __restrict__ an2,
    const float* __restrict__ ab3,
    const float* __restrict__ cb1, const float* __restrict__ cg1, const float* __restrict__ cn1,
    const float* __restrict__ cb2, const float* __restrict__ cg2, const float* __restrict__ cn2,
    const float* __restrict__ cb3,
    const __hip_bfloat16* __restrict__ wbuf,
    float* __restrict__ deltas, float* __restrict__ out) {
  __shared__ char smem[4][10240];   // per wave: xbuf 2KB + act 8KB
  const int tid = threadIdx.x;
  const int wave = tid >> 6, lane = tid & 63;
  const int c = lane & 15, q = lane >> 4;
  void* X   = (void*)smem[wave];
  void* ACT = (void*)(smem[wave] + 2048);
  const int base = blockIdx.x * 64 + wave * 16;   // 16 timesteps per wave

  // ---- states tile loaded ONCE (actor + critic share it) ----
  load_x(states + (size_t)base * 64, X, lane);
  __syncthreads();

  // ---- ACTOR(states) ----
  layer_ln<64>(X, 128, wbuf + OFF_AW1T, ab1, ag1, an1, ACT, c, q);
  __syncthreads();
  layer_ln<256>(ACT, 512, wbuf + OFF_AW2T, ab2, ag2, an2, ACT, c, q);
  __syncthreads();
  {
    f32x4 p3[2];
    run_small<256, 2>(ACT, 512, wbuf + OFF_AW3T, c, q, p3);
    softmax_write(p3, ab3, out, base, c, q);
  }
  __syncthreads();

  // ---- CRITIC(states) ---- (X still intact)
  layer_ln<64>(X, 128, wbuf + OFF_CW1T, cb1, cg1, cn1, ACT, c, q);
  __syncthreads();
  layer_ln<256>(ACT, 512, wbuf + OFF_CW2T, cb2, cg2, cn2, ACT, c, q);
  __syncthreads();
  float vst[4];
  {
    f32x4 v[1];
    run_small<256, 1>(ACT, 512, wbuf + OFF_CW3T, c, q, v);
    const float b3 = cb3[0];
#pragma unroll
    for (int r = 0; r < 4; ++r) vst[r] = v[0][r] + b3;
  }
  __syncthreads();

  // ---- CRITIC(next_states) ----
  load_x(next_states + (size_t)base * 64, X, lane);
  __syncthreads();
  layer_ln<64>(X, 128, wbuf + OFF_CW1T, cb1, cg1, cn1, ACT, c, q);
  __syncthreads();
  layer_ln<256>(ACT, 512, wbuf + OFF_CW2T, cb2, cg2, cn2, ACT, c, q);
  __syncthreads();
  {
    f32x4 v[1];
    run_small<256, 1>(ACT, 512, wbuf + OFF_CW3T, c, q, v);
    const float b3 = cb3[0];
    if (c == 0) {
#pragma unroll
      for (int r = 0; r < 4; ++r) {
        const int gr = base + q * 4 + r;
        const float nv = v[0][r] + b3;
        out[(size_t)gr * 20 + 19] = vst[r];   // stash value; gae -> return
        deltas[gr] = rewards[gr] + 0.99f * nv * masks[gr] - vst[r];
      }
    }
  }
}

// ---------------------------------------------------------------------------
// GAE, wave-parallel: each wave owns a 512-elem chunk + 512-elem lookahead.
// Per lane: 16 contiguous elems -> local affine (A,P); log-step shfl_down
// suffix composition; exclusive carry; local rescan + RMW out.
// Truncation: GL^512 ~ 2e-14.
__global__ __launch_bounds__(256) void gae_kernel(
    const float* __restrict__ deltas, const float* __restrict__ masks,
    float* __restrict__ out) {
  const int w = (blockIdx.x * blockDim.x + threadIdx.x) >> 6;  // 0..1023
  const int lane = threadIdx.x & 63;
  const int base = w * 512;
  const int idx0 = base + lane * 16;

  float d[16], cf[16];
  if (idx0 < T_SZ) {
#pragma unroll
    for (int i = 0; i < 4; ++i) {
      *(float4*)(d + i * 4)  = *(const float4*)(deltas + idx0 + i * 4);
      *(float4*)(cf + i * 4) = *(const float4*)(masks + idx0 + i * 4);
    }
#pragma unroll
    for (int i = 0; i < 16; ++i) cf[i] *= GL;
  } else {
#pragma unroll
    for (int i = 0; i < 16; ++i) { d[i] = 0.f; cf[i] = 0.f; }
  }

  // local affine: applying this block to incoming g gives A + P*g
  float A = 0.f, P = 1.f;
#pragma unroll
  for (int i = 15; i >= 0; --i) { A = d[i] + cf[i] * A; P *= cf[i]; }

  // suffix-inclusive scan over lanes (Hillis-Steele, compose rightward)
  float As = A, Ps = P;
#pragma unroll
  for (int st = 1; st < 64; st <<= 1) {
    float An = __shfl_down(As, st, 64);
    float Pn = __shfl_down(Ps, st, 64);
    if (lane + st < 64) { As = As + Ps * An; Ps = Ps * Pn; }
  }
  float G = __shfl_down(As, 1, 64);   // exclusive: lanes l+1..63
  if (lane == 63) G = 0.f;

  if (lane < 32) {                    // first 512 elems are this wave's output
    float g = G;
#pragma unroll
    for (int i = 15; i >= 0; --i) {
      g = d[i] + cf[i] * g;
      const size_t j = (size_t)(idx0 + i);
      float val = out[j * 20 + 19];
      out[j * 20 + 18] = g;
      out[j * 20 + 19] = g + val;
    }
  }
}

// ---------------------------------------------------------------------------
extern "C" void kernel_launch(void* const* d_in, const int* in_sizes, int n_in,
                              void* d_out, int out_size, void* d_ws, size_t ws_size,
                              hipStream_t stream) {
  const float* states      = (const float*)d_in[0];
  const float* next_states = (const float*)d_in[1];
  const float* rewards     = (const float*)d_in[2];
  const float* masks       = (const float*)d_in[3];
  const float* aw1 = (const float*)d_in[4];
  const float* ab1 = (const float*)d_in[5];
  const float* ag1 = (const float*)d_in[6];
  const float* an1 = (const float*)d_in[7];
  const float* aw2 = (const float*)d_in[8];
  const float* ab2 = (const float*)d_in[9];
  const float* ag2 = (const float*)d_in[10];
  const float* an2 = (const float*)d_in[11];
  const float* aw3 = (const float*)d_in[12];
  const float* ab3 = (const float*)d_in[13];
  const float* cw1 = (const float*)d_in[14];
  const float* cb1 = (const float*)d_in[15];
  const float* cg1 = (const float*)d_in[16];
  const float* cn1 = (const float*)d_in[17];
  const float* cw2 = (const float*)d_in[18];
  const float* cb2 = (const float*)d_in[19];
  const float* cg2 = (const float*)d_in[20];
  const float* cn2 = (const float*)d_in[21];
  const float* cw3 = (const float*)d_in[22];
  const float* cb3 = (const float*)d_in[23];

  __hip_bfloat16* wbuf = (__hip_bfloat16*)d_ws;
  float* deltas = (float*)((char*)d_ws + OFF_DELTAS_BYTES);
  float* out = (float*)d_out;

  prep_weights<<<(W_ELEMS + 255) / 256, 256, 0, stream>>>(aw1, aw2, aw3, cw1, cw2, cw3, wbuf);
  mlp_kernel<<<T_SZ / 64, 256, 0, stream>>>(
      states, next_states, rewards, masks,
      ab1, ag1, an1, ab2, ag2, an2, ab3,
      cb1, cg1, cn1, cb2, cg2, cn2, cb3,
      wbuf, deltas, out);
  gae_kernel<<<256, 256, 0, stream>>>(deltas, masks, out);
}

// Round 5
// 3280.231 us; speedup vs baseline: 1.8895x; 1.0326x over previous
//
#include <hip/hip_runtime.h>
#include <hip/hip_bf16.h>

// ============================================================================
// PPO agent fused forward (round 5):
//  r1-r4 root cause: gfx950 splits the unified register file into arch/AGPR
//  halves when MFMA is used (observed: reported VGPR = half the budget each
//  round). LN epilogue state (pk[32]+s/ss+frags ~70 regs) can't fit the 64-reg
//  arch half at 4 waves/EU -> structural spill (4+ GB scratch writes).
//  Fix: stash pre-LN bf16-packed values in the idle AGPR half via inline-asm
//  v_accvgpr_write/read ("a" constraint). Arch-side live state ~35 regs.
//  sched_barrier(0) every 2 k-steps caps load-prefetch hoisting (~24 regs).
//  Kept from r4: column-pair streaming, shared states load, wave-parallel GAE.
// ============================================================================

#define T_SZ 524288
#define GL 0.9405f   // GAMMA*LAM

typedef __attribute__((ext_vector_type(8))) short bf16x8;   // 8 bf16 (4 VGPRs)
typedef __attribute__((ext_vector_type(4))) float f32x4;

// ws layout (bf16 elements); weights stored [N][K], k-permuted
#define OFF_AW1T 0        // [256][64]
#define OFF_AW2T 16384    // [256][256]
#define OFF_AW3T 81920    // [32][256]  rows >=18 zero
#define OFF_CW1T 90112    // [256][64]
#define OFF_CW2T 106496   // [256][256]
#define OFF_CW3T 172032   // [16][256]  rows >=1 zero
#define W_ELEMS  176128
#define OFF_DELTAS_BYTES 352256

// k = p*32 + h*16 + w (w=k&15, h=(k>>4)&1) -> pos = p*32 + w*2 + h
// Applied to BOTH A (LDS) and B (weights) -> MFMA k-sum invariant.
__device__ __forceinline__ int perm_k(int k) {
  return (k & ~31) | ((k & 15) << 1) | ((k >> 4) & 1);
}

// 16B-granular XOR swizzle
__device__ __forceinline__ void* lds_at(void* base, int row, int colByte, int strideB) {
  return (char*)base + row * strideB + (colByte ^ ((row & 7) << 4));
}

__device__ __forceinline__ unsigned pack2(float a, float b) {
  union { __hip_bfloat16 h; unsigned short u; } ua, ub;
  ua.h = __float2bfloat16(a); ub.h = __float2bfloat16(b);
  return (unsigned)ua.u | ((unsigned)ub.u << 16);
}

__device__ __forceinline__ void unpack2(unsigned u, float& a, float& b) {
  union { unsigned u; float f; } x, y;
  x.u = u << 16; y.u = u & 0xFFFF0000u;
  a = x.f; b = y.f;
}

// AGPR stash: park a u32 in the accumulator half of the register file
__device__ __forceinline__ void ag_put(unsigned& slot, unsigned v) {
  asm("v_accvgpr_write_b32 %0, %1" : "=a"(slot) : "v"(v));
}
__device__ __forceinline__ unsigned ag_get(unsigned& slot) {
  unsigned v;
  asm("v_accvgpr_read_b32 %0, %1" : "=v"(v) : "a"(slot));
  return v;
}

// ---------------------------------------------------------------------------
// Linear(K->256) + bias + LayerNorm + ReLU, column-pair streaming.
// A from LDS (rows=c), B from global [N][K] k-permuted bf16.
// Pre-LN values live bf16-packed in 32 AGPRs; post-LN written to Obuf
// (Obuf may equal Abuf: all A-reads complete before stores).
template<int K>
__device__ __forceinline__ void layer_ln(void* Abuf, int astrB,
    const __hip_bfloat16* __restrict__ Wt,
    const float* __restrict__ bias, const float* __restrict__ gam,
    const float* __restrict__ bet, void* Obuf, int c, int q) {
  float s[4] = {0, 0, 0, 0}, ss[4] = {0, 0, 0, 0};
  unsigned ag[32];   // AGPR-resident via ag_put/ag_get (static indices only)
#pragma unroll
  for (int p = 0; p < 8; ++p) {
    f32x4 acc0 = {0.f, 0.f, 0.f, 0.f}, acc1 = {0.f, 0.f, 0.f, 0.f};
    const __hip_bfloat16* wp = Wt + ((size_t)(2 * p) * 16 + c) * K + q * 8;
#pragma unroll
    for (int ks = 0; ks < K / 32; ++ks) {
      bf16x8 a = *(const bf16x8*)lds_at(Abuf, c, ks * 64 + q * 16, astrB);
      bf16x8 b0 = *(const bf16x8*)(wp + ks * 32);
      bf16x8 b1 = *(const bf16x8*)(wp + (size_t)16 * K + ks * 32);
      acc0 = __builtin_amdgcn_mfma_f32_16x16x32_bf16(a, b0, acc0, 0, 0, 0);
      acc1 = __builtin_amdgcn_mfma_f32_16x16x32_bf16(a, b1, acc1, 0, 0, 0);
      if ((ks & 1) == 1) __builtin_amdgcn_sched_barrier(0);  // cap prefetch window
    }
    const float bb0 = bias[2 * p * 16 + c], bb1 = bias[(2 * p + 1) * 16 + c];
#pragma unroll
    for (int r = 0; r < 4; ++r) {
      float v0 = acc0[r] + bb0, v1 = acc1[r] + bb1;
      s[r] += v0 + v1;
      ss[r] += v0 * v0 + v1 * v1;
      ag_put(ag[p * 4 + r], pack2(v0, v1));
    }
    __builtin_amdgcn_sched_barrier(0);
  }
  // row sums over the 16 c-lanes (lane = q*16+c; xor m<16 flips c only)
#pragma unroll
  for (int m = 1; m < 16; m <<= 1) {
#pragma unroll
    for (int r = 0; r < 4; ++r) {
      s[r]  += __shfl_xor(s[r],  m, 64);
      ss[r] += __shfl_xor(ss[r], m, 64);
    }
  }
  float mean[4], rs[4];
#pragma unroll
  for (int r = 0; r < 4; ++r) {
    mean[r] = s[r] * (1.f / 256.f);
    float var = ss[r] * (1.f / 256.f) - mean[r] * mean[r];
    rs[r] = rsqrtf(var + 1e-5f);
  }
#pragma unroll
  for (int p = 0; p < 8; ++p) {
    const float g0 = gam[2 * p * 16 + c],       b0 = bet[2 * p * 16 + c];
    const float g1 = gam[(2 * p + 1) * 16 + c], b1 = bet[(2 * p + 1) * 16 + c];
#pragma unroll
    for (int r = 0; r < 4; ++r) {
      float v0, v1;
      unpack2(ag_get(ag[p * 4 + r]), v0, v1);
      float w0 = fmaxf((v0 - mean[r]) * rs[r] * g0 + b0, 0.f);
      float w1 = fmaxf((v1 - mean[r]) * rs[r] * g1 + b1, 0.f);
      *(unsigned*)lds_at(Obuf, q * 4 + r, p * 64 + c * 4, 512) = pack2(w0, w1);
    }
  }
}

// small final GEMM (no LN): NT column-tiles of 16
template<int K, int NT>
__device__ __forceinline__ void run_small(void* Abuf, int astrB,
    const __hip_bfloat16* __restrict__ Wt, int c, int q, f32x4* acc) {
#pragma unroll
  for (int nt = 0; nt < NT; ++nt) acc[nt] = (f32x4){0.f, 0.f, 0.f, 0.f};
#pragma unroll
  for (int ks = 0; ks < K / 32; ++ks) {
    bf16x8 a = *(const bf16x8*)lds_at(Abuf, c, ks * 64 + q * 16, astrB);
#pragma unroll
    for (int nt = 0; nt < NT; ++nt) {
      bf16x8 b = *(const bf16x8*)(Wt + ((size_t)nt * 16 + c) * K + ks * 32 + q * 8);
      acc[nt] = __builtin_amdgcn_mfma_f32_16x16x32_bf16(a, b, acc[nt], 0, 0, 0);
    }
    if ((ks & 1) == 1) __builtin_amdgcn_sched_barrier(0);
  }
}

// load 16 rows x 64 cols fp32 -> bf16 k-permuted swizzled LDS (stride 128B)
__device__ __forceinline__ void load_x(const float* __restrict__ src, void* W, int lane) {
  const int row = lane >> 2, m = lane & 3;
  const int p = m >> 1, half = m & 1;
  const int kb = p * 32 + half * 8;
  const float* rp = src + (size_t)row * 64;
  float4 x0a = *(const float4*)(rp + kb);
  float4 x0b = *(const float4*)(rp + kb + 4);
  float4 x1a = *(const float4*)(rp + kb + 16);
  float4 x1b = *(const float4*)(rp + kb + 20);
  unsigned u[8];
  u[0] = pack2(x0a.x, x1a.x); u[1] = pack2(x0a.y, x1a.y);
  u[2] = pack2(x0a.z, x1a.z); u[3] = pack2(x0a.w, x1a.w);
  u[4] = pack2(x0b.x, x1b.x); u[5] = pack2(x0b.y, x1b.y);
  u[6] = pack2(x0b.z, x1b.z); u[7] = pack2(x0b.w, x1b.w);
  const int byte0 = p * 64 + half * 32;
  *(uint4*)lds_at(W, row, byte0, 128)      = *(uint4*)(u);
  *(uint4*)lds_at(W, row, byte0 + 16, 128) = *(uint4*)(u + 4);
}

__device__ __forceinline__ void softmax_write(f32x4* acc3,
    const float* __restrict__ ab3, float* __restrict__ out,
    int grow0, int c, int q) {
  float b0 = ab3[c];
  float b1 = (c < 2) ? ab3[16 + c] : 0.f;
#pragma unroll
  for (int r = 0; r < 4; ++r) {
    float x0 = acc3[0][r] + b0;
    float x1 = (c < 2) ? (acc3[1][r] + b1) : -1e30f;
    float mx = fmaxf(x0, x1);
#pragma unroll
    for (int m = 1; m < 16; m <<= 1) mx = fmaxf(mx, __shfl_xor(mx, m, 64));
    float e0 = __expf(x0 - mx);
    float e1 = (c < 2) ? __expf(x1 - mx) : 0.f;
    float sm = e0 + e1;
#pragma unroll
    for (int m = 1; m < 16; m <<= 1) sm += __shfl_xor(sm, m, 64);
    float inv = 1.f / sm;
    int gr = grow0 + q * 4 + r;
    out[(size_t)gr * 20 + c] = e0 * inv;
    if (c < 2) out[(size_t)gr * 20 + 16 + c] = e1 * inv;
  }
}

// ---------------------------------------------------------------------------
__global__ void prep_weights(const float* __restrict__ aw1, const float* __restrict__ aw2,
                             const float* __restrict__ aw3, const float* __restrict__ cw1,
                             const float* __restrict__ cw2, const float* __restrict__ cw3,
                             __hip_bfloat16* __restrict__ wb) {
  int i = blockIdx.x * 256 + threadIdx.x;
  if (i >= W_ELEMS) return;
  float v; int dst;
  if (i < OFF_AW2T)      { int j = i;            int n = j >> 6, k = j & 63;  v = aw1[k * 256 + n];              dst = OFF_AW1T + n * 64  + perm_k(k); }
  else if (i < OFF_AW3T) { int j = i - OFF_AW2T; int n = j >> 8, k = j & 255; v = aw2[k * 256 + n];              dst = OFF_AW2T + n * 256 + perm_k(k); }
  else if (i < OFF_CW1T) { int j = i - OFF_AW3T; int n = j >> 8, k = j & 255; v = (n < 18) ? aw3[k * 18 + n] : 0.f; dst = OFF_AW3T + n * 256 + perm_k(k); }
  else if (i < OFF_CW2T) { int j = i - OFF_CW1T; int n = j >> 6, k = j & 63;  v = cw1[k * 256 + n];              dst = OFF_CW1T + n * 64  + perm_k(k); }
  else if (i < OFF_CW3T) { int j = i - OFF_CW2T; int n = j >> 8, k = j & 255; v = cw2[k * 256 + n];              dst = OFF_CW2T + n * 256 + perm_k(k); }
  else                   { int j = i - OFF_CW3T; int n = j >> 8, k = j & 255; v = (n == 0) ? cw3[k] : 0.f;       dst = OFF_CW3T + n * 256 + perm_k(k); }
  wb[dst] = __float2bfloat16(v);
}

// ---------------------------------------------------------------------------
__global__ __launch_bounds__(256, 4) void mlp_kernel(
    const float* __restrict__ states, const float* __restrict__ next_states,
    const float* __restrict__ rewards, const float* __restrict__ masks,
    const float* __restrict__ ab1, const float* __restrict__ ag1, const float* __restrict__ an1,
    const float* __restrict__ ab2, const float* __restrict__ ag2, const float* __restrict__ an2,
    const float* __restrict__ ab3,
    const float* __restrict__ cb1, const float* __restrict__ cg1, const float* __restrict__ cn1,
    const float* __restrict__ cb2, const float* __restrict__ cg2, const float* __restrict__ cn2,
    const float* __restrict__ cb3,
    const __hip_bfloat16* __restrict__ wbuf,
    float* __restrict__ deltas, float* __restrict__ out) {
  __shared__ char smem[4][10240];   // per wave: xbuf 2KB + act 8KB
  const int tid = threadIdx.x;
  const int wave = tid >> 6, lane = tid & 63;
  const int c = lane & 15, q = lane >> 4;
  void* X   = (void*)smem[wave];
  void* ACT = (void*)(smem[wave] + 2048);
  const int base = blockIdx.x * 64 + wave * 16;   // 16 timesteps per wave

  // ---- states tile loaded ONCE (actor + critic share it) ----
  load_x(states + (size_t)base * 64, X, lane);
  __syncthreads();

  // ---- ACTOR(states) ----
  layer_ln<64>(X, 128, wbuf + OFF_AW1T, ab1, ag1, an1, ACT, c, q);
  __syncthreads();
  layer_ln<256>(ACT, 512, wbuf + OFF_AW2T, ab2, ag2, an2, ACT, c, q);
  __syncthreads();
  {
    f32x4 p3[2];
    run_small<256, 2>(ACT, 512, wbuf + OFF_AW3T, c, q, p3);
    softmax_write(p3, ab3, out, base, c, q);
  }
  __syncthreads();

  // ---- CRITIC(states) ---- (X still intact)
  layer_ln<64>(X, 128, wbuf + OFF_CW1T, cb1, cg1, cn1, ACT, c, q);
  __syncthreads();
  layer_ln<256>(ACT, 512, wbuf + OFF_CW2T, cb2, cg2, cn2, ACT, c, q);
  __syncthreads();
  float vst[4];
  {
    f32x4 v[1];
    run_small<256, 1>(ACT, 512, wbuf + OFF_CW3T, c, q, v);
    const float b3 = cb3[0];
#pragma unroll
    for (int r = 0; r < 4; ++r) vst[r] = v[0][r] + b3;
  }
  __syncthreads();

  // ---- CRITIC(next_states) ----
  load_x(next_states + (size_t)base * 64, X, lane);
  __syncthreads();
  layer_ln<64>(X, 128, wbuf + OFF_CW1T, cb1, cg1, cn1, ACT, c, q);
  __syncthreads();
  layer_ln<256>(ACT, 512, wbuf + OFF_CW2T, cb2, cg2, cn2, ACT, c, q);
  __syncthreads();
  {
    f32x4 v[1];
    run_small<256, 1>(ACT, 512, wbuf + OFF_CW3T, c, q, v);
    const float b3 = cb3[0];
    if (c == 0) {
#pragma unroll
      for (int r = 0; r < 4; ++r) {
        const int gr = base + q * 4 + r;
        const float nv = v[0][r] + b3;
        out[(size_t)gr * 20 + 19] = vst[r];   // stash value; gae -> return
        deltas[gr] = rewards[gr] + 0.99f * nv * masks[gr] - vst[r];
      }
    }
  }
}

// ---------------------------------------------------------------------------
// GAE, wave-parallel: each wave owns a 512-elem chunk + 512-elem lookahead.
// Per lane: 16 contiguous elems -> local affine (A,P); log-step shfl_down
// suffix composition; exclusive carry; local rescan + RMW out.
// Truncation: GL^512 ~ 2e-14.
__global__ __launch_bounds__(256) void gae_kernel(
    const float* __restrict__ deltas, const float* __restrict__ masks,
    float* __restrict__ out) {
  const int w = (blockIdx.x * blockDim.x + threadIdx.x) >> 6;  // 0..1023
  const int lane = threadIdx.x & 63;
  const int base = w * 512;
  const int idx0 = base + lane * 16;

  float d[16], cf[16];
  if (idx0 < T_SZ) {
#pragma unroll
    for (int i = 0; i < 4; ++i) {
      *(float4*)(d + i * 4)  = *(const float4*)(deltas + idx0 + i * 4);
      *(float4*)(cf + i * 4) = *(const float4*)(masks + idx0 + i * 4);
    }
#pragma unroll
    for (int i = 0; i < 16; ++i) cf[i] *= GL;
  } else {
#pragma unroll
    for (int i = 0; i < 16; ++i) { d[i] = 0.f; cf[i] = 0.f; }
  }

  // local affine: applying this block to incoming g gives A + P*g
  float A = 0.f, P = 1.f;
#pragma unroll
  for (int i = 15; i >= 0; --i) { A = d[i] + cf[i] * A; P *= cf[i]; }

  // suffix-inclusive scan over lanes (Hillis-Steele, compose rightward)
  float As = A, Ps = P;
#pragma unroll
  for (int st = 1; st < 64; st <<= 1) {
    float An = __shfl_down(As, st, 64);
    float Pn = __shfl_down(Ps, st, 64);
    if (lane + st < 64) { As = As + Ps * An; Ps = Ps * Pn; }
  }
  float G = __shfl_down(As, 1, 64);   // exclusive: lanes l+1..63
  if (lane == 63) G = 0.f;

  if (lane < 32) {                    // first 512 elems are this wave's output
    float g = G;
#pragma unroll
    for (int i = 15; i >= 0; --i) {
      g = d[i] + cf[i] * g;
      const size_t j = (size_t)(idx0 + i);
      float val = out[j * 20 + 19];
      out[j * 20 + 18] = g;
      out[j * 20 + 19] = g + val;
    }
  }
}

// ---------------------------------------------------------------------------
extern "C" void kernel_launch(void* const* d_in, const int* in_sizes, int n_in,
                              void* d_out, int out_size, void* d_ws, size_t ws_size,
                              hipStream_t stream) {
  const float* states      = (const float*)d_in[0];
  const float* next_states = (const float*)d_in[1];
  const float* rewards     = (const float*)d_in[2];
  const float* masks       = (const float*)d_in[3];
  const float* aw1 = (const float*)d_in[4];
  const float* ab1 = (const float*)d_in[5];
  const float* ag1 = (const float*)d_in[6];
  const float* an1 = (const float*)d_in[7];
  const float* aw2 = (const float*)d_in[8];
  const float* ab2 = (const float*)d_in[9];
  const float* ag2 = (const float*)d_in[10];
  const float* an2 = (const float*)d_in[11];
  const float* aw3 = (const float*)d_in[12];
  const float* ab3 = (const float*)d_in[13];
  const float* cw1 = (const float*)d_in[14];
  const float* cb1 = (const float*)d_in[15];
  const float* cg1 = (const float*)d_in[16];
  const float* cn1 = (const float*)d_in[17];
  const float* cw2 = (const float*)d_in[18];
  const float* cb2 = (const float*)d_in[19];
  const float* cg2 = (const float*)d_in[20];
  const float* cn2 = (const float*)d_in[21];
  const float* cw3 = (const float*)d_in[22];
  const float* cb3 = (const float*)d_in[23];

  __hip_bfloat16* wbuf = (__hip_bfloat16*)d_ws;
  float* deltas = (float*)((char*)d_ws + OFF_DELTAS_BYTES);
  float* out = (float*)d_out;

  prep_weights<<<(W_ELEMS + 255) / 256, 256, 0, stream>>>(aw1, aw2, aw3, cw1, cw2, cw3, wbuf);
  mlp_kernel<<<T_SZ / 64, 256, 0, stream>>>(
      states, next_states, rewards, masks,
      ab1, ag1, an1, ab2, ag2, an2, ab3,
      cb1, cg1, cn1, cb2, cg2, cn2, cb3,
      wbuf, deltas, out);
  gae_kernel<<<256, 256, 0, stream>>>(deltas, masks, out);
}

// Round 6
// 2032.538 us; speedup vs baseline: 3.0495x; 1.6139x over previous
//
#include <hip/hip_runtime.h>
#include <hip/hip_bf16.h>

// ============================================================================
// PPO agent fused forward (round 6):
//  r1-r5 root cause: with MFMA present the allocator gives the arch VGPR side
//  only HALF the per-wave budget (observed: reported VGPR = budget/2 in all 5
//  rounds). LN epilogue needed ~75 arch regs -> structural spill at the 64 cap.
//  Fix A: TWO-PASS LN -- no register stash at all. Pass 1 stores pre-LN bf16
//  pairs straight into the destination LDS buffer (ping-pong, no in-place
//  hazard); pass 2 RMWs each u32 (normalize+ReLU). Peak arch demand ~45 regs.
//  Fix B: 128-thread blocks + __launch_bounds__(128,2): budget 256/wave,
//  LDS 36KB/block -> 4 blocks/CU = 8 waves/CU regardless of regs.
//  Numerics identical to r4 (same bf16 pre-LN rounding): absmax ~0.125.
// ============================================================================

#define T_SZ 524288
#define GL 0.9405f   // GAMMA*LAM

typedef __attribute__((ext_vector_type(8))) short bf16x8;   // 8 bf16 (4 VGPRs)
typedef __attribute__((ext_vector_type(4))) float f32x4;

// ws layout (bf16 elements); weights stored [N][K], k-permuted
#define OFF_AW1T 0        // [256][64]
#define OFF_AW2T 16384    // [256][256]
#define OFF_AW3T 81920    // [32][256]  rows >=18 zero
#define OFF_CW1T 90112    // [256][64]
#define OFF_CW2T 106496   // [256][256]
#define OFF_CW3T 172032   // [16][256]  rows >=1 zero
#define W_ELEMS  176128
#define OFF_DELTAS_BYTES 352256

// k = p*32 + h*16 + w (w=k&15, h=(k>>4)&1) -> pos = p*32 + w*2 + h
// Applied to BOTH A (LDS) and B (weights) -> MFMA k-sum invariant.
__device__ __forceinline__ int perm_k(int k) {
  return (k & ~31) | ((k & 15) << 1) | ((k >> 4) & 1);
}

// 16B-granular XOR swizzle
__device__ __forceinline__ void* lds_at(void* base, int row, int colByte, int strideB) {
  return (char*)base + row * strideB + (colByte ^ ((row & 7) << 4));
}

__device__ __forceinline__ unsigned pack2(float a, float b) {
  union { __hip_bfloat16 h; unsigned short u; } ua, ub;
  ua.h = __float2bfloat16(a); ub.h = __float2bfloat16(b);
  return (unsigned)ua.u | ((unsigned)ub.u << 16);
}

__device__ __forceinline__ void unpack2(unsigned u, float& a, float& b) {
  union { unsigned u; float f; } x, y;
  x.u = u << 16; y.u = u & 0xFFFF0000u;
  a = x.f; b = y.f;
}

// ---------------------------------------------------------------------------
// Linear(K->256) + bias + LayerNorm + ReLU, two-pass over LDS.
// Pass 1: per column-pair MFMA -> bias -> s/ss -> store pre-LN bf16 pair to
// Obuf (Obuf != Abuf). Reduce. Pass 2: RMW each u32: normalize+ReLU.
// No register stash -> peak arch pressure ~45 regs.
template<int K>
__device__ __forceinline__ void layer_ln(void* Abuf, int astrB,
    const __hip_bfloat16* __restrict__ Wt,
    const float* __restrict__ bias, const float* __restrict__ gam,
    const float* __restrict__ bet, void* Obuf, int c, int q) {
  float s[4] = {0, 0, 0, 0}, ss[4] = {0, 0, 0, 0};
#pragma unroll
  for (int p = 0; p < 8; ++p) {
    f32x4 acc0 = {0.f, 0.f, 0.f, 0.f}, acc1 = {0.f, 0.f, 0.f, 0.f};
    const __hip_bfloat16* wp = Wt + ((size_t)(2 * p) * 16 + c) * K + q * 8;
#pragma unroll
    for (int ks = 0; ks < K / 32; ++ks) {
      bf16x8 a = *(const bf16x8*)lds_at(Abuf, c, ks * 64 + q * 16, astrB);
      bf16x8 b0 = *(const bf16x8*)(wp + ks * 32);
      bf16x8 b1 = *(const bf16x8*)(wp + (size_t)16 * K + ks * 32);
      acc0 = __builtin_amdgcn_mfma_f32_16x16x32_bf16(a, b0, acc0, 0, 0, 0);
      acc1 = __builtin_amdgcn_mfma_f32_16x16x32_bf16(a, b1, acc1, 0, 0, 0);
    }
    const float bb0 = bias[32 * p + c], bb1 = bias[32 * p + 16 + c];
#pragma unroll
    for (int r = 0; r < 4; ++r) {
      float v0 = acc0[r] + bb0, v1 = acc1[r] + bb1;
      s[r] += v0 + v1;
      ss[r] += v0 * v0 + v1 * v1;
      *(unsigned*)lds_at(Obuf, q * 4 + r, p * 64 + c * 4, 512) = pack2(v0, v1);
    }
  }
  // row sums over the 16 c-lanes (lane = q*16+c; xor m<16 flips c only)
#pragma unroll
  for (int m = 1; m < 16; m <<= 1) {
#pragma unroll
    for (int r = 0; r < 4; ++r) {
      s[r]  += __shfl_xor(s[r],  m, 64);
      ss[r] += __shfl_xor(ss[r], m, 64);
    }
  }
  float mean[4], rs[4];
#pragma unroll
  for (int r = 0; r < 4; ++r) {
    mean[r] = s[r] * (1.f / 256.f);
    float var = ss[r] * (1.f / 256.f) - mean[r] * mean[r];
    rs[r] = rsqrtf(var + 1e-5f);
  }
  // pass 2: in-place normalize + ReLU (per-lane RMW of its own slots)
#pragma unroll
  for (int p = 0; p < 8; ++p) {
    const float g0 = gam[32 * p + c],      b0 = bet[32 * p + c];
    const float g1 = gam[32 * p + 16 + c], b1 = bet[32 * p + 16 + c];
#pragma unroll
    for (int r = 0; r < 4; ++r) {
      unsigned* ap = (unsigned*)lds_at(Obuf, q * 4 + r, p * 64 + c * 4, 512);
      float v0, v1;
      unpack2(*ap, v0, v1);
      float w0 = fmaxf((v0 - mean[r]) * rs[r] * g0 + b0, 0.f);
      float w1 = fmaxf((v1 - mean[r]) * rs[r] * g1 + b1, 0.f);
      *ap = pack2(w0, w1);
    }
  }
}

// small final GEMM (no LN): NT column-tiles of 16
template<int K, int NT>
__device__ __forceinline__ void run_small(void* Abuf, int astrB,
    const __hip_bfloat16* __restrict__ Wt, int c, int q, f32x4* acc) {
#pragma unroll
  for (int nt = 0; nt < NT; ++nt) acc[nt] = (f32x4){0.f, 0.f, 0.f, 0.f};
#pragma unroll
  for (int ks = 0; ks < K / 32; ++ks) {
    bf16x8 a = *(const bf16x8*)lds_at(Abuf, c, ks * 64 + q * 16, astrB);
#pragma unroll
    for (int nt = 0; nt < NT; ++nt) {
      bf16x8 b = *(const bf16x8*)(Wt + ((size_t)nt * 16 + c) * K + ks * 32 + q * 8);
      acc[nt] = __builtin_amdgcn_mfma_f32_16x16x32_bf16(a, b, acc[nt], 0, 0, 0);
    }
  }
}

// load 16 rows x 64 cols fp32 -> bf16 k-permuted swizzled LDS (stride 128B)
__device__ __forceinline__ void load_x(const float* __restrict__ src, void* W, int lane) {
  const int row = lane >> 2, m = lane & 3;
  const int p = m >> 1, half = m & 1;
  const int kb = p * 32 + half * 8;
  const float* rp = src + (size_t)row * 64;
  float4 x0a = *(const float4*)(rp + kb);
  float4 x0b = *(const float4*)(rp + kb + 4);
  float4 x1a = *(const float4*)(rp + kb + 16);
  float4 x1b = *(const float4*)(rp + kb + 20);
  unsigned u[8];
  u[0] = pack2(x0a.x, x1a.x); u[1] = pack2(x0a.y, x1a.y);
  u[2] = pack2(x0a.z, x1a.z); u[3] = pack2(x0a.w, x1a.w);
  u[4] = pack2(x0b.x, x1b.x); u[5] = pack2(x0b.y, x1b.y);
  u[6] = pack2(x0b.z, x1b.z); u[7] = pack2(x0b.w, x1b.w);
  const int byte0 = p * 64 + half * 32;
  *(uint4*)lds_at(W, row, byte0, 128)      = *(uint4*)(u);
  *(uint4*)lds_at(W, row, byte0 + 16, 128) = *(uint4*)(u + 4);
}

__device__ __forceinline__ void softmax_write(f32x4* acc3,
    const float* __restrict__ ab3, float* __restrict__ out,
    int grow0, int c, int q) {
  float b0 = ab3[c];
  float b1 = (c < 2) ? ab3[16 + c] : 0.f;
#pragma unroll
  for (int r = 0; r < 4; ++r) {
    float x0 = acc3[0][r] + b0;
    float x1 = (c < 2) ? (acc3[1][r] + b1) : -1e30f;
    float mx = fmaxf(x0, x1);
#pragma unroll
    for (int m = 1; m < 16; m <<= 1) mx = fmaxf(mx, __shfl_xor(mx, m, 64));
    float e0 = __expf(x0 - mx);
    float e1 = (c < 2) ? __expf(x1 - mx) : 0.f;
    float sm = e0 + e1;
#pragma unroll
    for (int m = 1; m < 16; m <<= 1) sm += __shfl_xor(sm, m, 64);
    float inv = 1.f / sm;
    int gr = grow0 + q * 4 + r;
    out[(size_t)gr * 20 + c] = e0 * inv;
    if (c < 2) out[(size_t)gr * 20 + 16 + c] = e1 * inv;
  }
}

// ---------------------------------------------------------------------------
__global__ void prep_weights(const float* __restrict__ aw1, const float* __restrict__ aw2,
                             const float* __restrict__ aw3, const float* __restrict__ cw1,
                             const float* __restrict__ cw2, const float* __restrict__ cw3,
                             __hip_bfloat16* __restrict__ wb) {
  int i = blockIdx.x * 256 + threadIdx.x;
  if (i >= W_ELEMS) return;
  float v; int dst;
  if (i < OFF_AW2T)      { int j = i;            int n = j >> 6, k = j & 63;  v = aw1[k * 256 + n];              dst = OFF_AW1T + n * 64  + perm_k(k); }
  else if (i < OFF_AW3T) { int j = i - OFF_AW2T; int n = j >> 8, k = j & 255; v = aw2[k * 256 + n];              dst = OFF_AW2T + n * 256 + perm_k(k); }
  else if (i < OFF_CW1T) { int j = i - OFF_AW3T; int n = j >> 8, k = j & 255; v = (n < 18) ? aw3[k * 18 + n] : 0.f; dst = OFF_AW3T + n * 256 + perm_k(k); }
  else if (i < OFF_CW2T) { int j = i - OFF_CW1T; int n = j >> 6, k = j & 63;  v = cw1[k * 256 + n];              dst = OFF_CW1T + n * 64  + perm_k(k); }
  else if (i < OFF_CW3T) { int j = i - OFF_CW2T; int n = j >> 8, k = j & 255; v = cw2[k * 256 + n];              dst = OFF_CW2T + n * 256 + perm_k(k); }
  else                   { int j = i - OFF_CW3T; int n = j >> 8, k = j & 255; v = (n == 0) ? cw3[k] : 0.f;       dst = OFF_CW3T + n * 256 + perm_k(k); }
  wb[dst] = __float2bfloat16(v);
}

// ---------------------------------------------------------------------------
__global__ __launch_bounds__(128, 2) void mlp_kernel(
    const float* __restrict__ states, const float* __restrict__ next_states,
    const float* __restrict__ rewards, const float* __restrict__ masks,
    const float* __restrict__ ab1, const float* __restrict__ ag1, const float* __restrict__ an1,
    const float* __restrict__ ab2, const float* __restrict__ ag2, const float* __restrict__ an2,
    const float* __restrict__ ab3,
    const float* __restrict__ cb1, const float* __restrict__ cg1, const float* __restrict__ cn1,
    const float* __restrict__ cb2, const float* __restrict__ cg2, const float* __restrict__ cn2,
    const float* __restrict__ cb3,
    const __hip_bfloat16* __restrict__ wbuf,
    float* __restrict__ deltas, float* __restrict__ out) {
  __shared__ char smem[2][18432];   // per wave: X 2KB + ACT0 8KB + ACT1 8KB
  const int tid = threadIdx.x;
  const int wave = tid >> 6, lane = tid & 63;
  const int c = lane & 15, q = lane >> 4;
  char* sb = smem[wave];
  void* X  = (void*)sb;
  void* A0 = (void*)(sb + 2048);
  void* A1 = (void*)(sb + 10240);
  const int base = blockIdx.x * 32 + wave * 16;   // 16 timesteps per wave

  // ---- states tile loaded ONCE (actor + critic share it) ----
  load_x(states + (size_t)base * 64, X, lane);
  __syncthreads();

  // ---- ACTOR(states) ----
  layer_ln<64>(X, 128, wbuf + OFF_AW1T, ab1, ag1, an1, A0, c, q);
  __syncthreads();
  layer_ln<256>(A0, 512, wbuf + OFF_AW2T, ab2, ag2, an2, A1, c, q);
  __syncthreads();
  {
    f32x4 p3[2];
    run_small<256, 2>(A1, 512, wbuf + OFF_AW3T, c, q, p3);
    softmax_write(p3, ab3, out, base, c, q);
  }
  __syncthreads();

  // ---- CRITIC(states) ---- (X still intact)
  layer_ln<64>(X, 128, wbuf + OFF_CW1T, cb1, cg1, cn1, A0, c, q);
  __syncthreads();
  layer_ln<256>(A0, 512, wbuf + OFF_CW2T, cb2, cg2, cn2, A1, c, q);
  __syncthreads();
  float vst[4];
  {
    f32x4 v[1];
    run_small<256, 1>(A1, 512, wbuf + OFF_CW3T, c, q, v);
    const float b3 = cb3[0];
#pragma unroll
    for (int r = 0; r < 4; ++r) vst[r] = v[0][r] + b3;
  }
  __syncthreads();

  // ---- CRITIC(next_states) ----
  load_x(next_states + (size_t)base * 64, X, lane);
  __syncthreads();
  layer_ln<64>(X, 128, wbuf + OFF_CW1T, cb1, cg1, cn1, A0, c, q);
  __syncthreads();
  layer_ln<256>(A0, 512, wbuf + OFF_CW2T, cb2, cg2, cn2, A1, c, q);
  __syncthreads();
  {
    f32x4 v[1];
    run_small<256, 1>(A1, 512, wbuf + OFF_CW3T, c, q, v);
    const float b3 = cb3[0];
    if (c == 0) {
#pragma unroll
      for (int r = 0; r < 4; ++r) {
        const int gr = base + q * 4 + r;
        const float nv = v[0][r] + b3;
        out[(size_t)gr * 20 + 19] = vst[r];   // stash value; gae -> return
        deltas[gr] = rewards[gr] + 0.99f * nv * masks[gr] - vst[r];
      }
    }
  }
}

// ---------------------------------------------------------------------------
// GAE, wave-parallel: each wave owns a 512-elem chunk + 512-elem lookahead.
// Per lane: 16 contiguous elems -> local affine (A,P); log-step shfl_down
// suffix composition; exclusive carry; local rescan + RMW out.
// Truncation: GL^512 ~ 2e-14.
__global__ __launch_bounds__(256) void gae_kernel(
    const float* __restrict__ deltas, const float* __restrict__ masks,
    float* __restrict__ out) {
  const int w = (blockIdx.x * blockDim.x + threadIdx.x) >> 6;  // 0..1023
  const int lane = threadIdx.x & 63;
  const int base = w * 512;
  const int idx0 = base + lane * 16;

  float d[16], cf[16];
  if (idx0 < T_SZ) {
#pragma unroll
    for (int i = 0; i < 4; ++i) {
      *(float4*)(d + i * 4)  = *(const float4*)(deltas + idx0 + i * 4);
      *(float4*)(cf + i * 4) = *(const float4*)(masks + idx0 + i * 4);
    }
#pragma unroll
    for (int i = 0; i < 16; ++i) cf[i] *= GL;
  } else {
#pragma unroll
    for (int i = 0; i < 16; ++i) { d[i] = 0.f; cf[i] = 0.f; }
  }

  // local affine: applying this block to incoming g gives A + P*g
  float A = 0.f, P = 1.f;
#pragma unroll
  for (int i = 15; i >= 0; --i) { A = d[i] + cf[i] * A; P *= cf[i]; }

  // suffix-inclusive scan over lanes (Hillis-Steele, compose rightward)
  float As = A, Ps = P;
#pragma unroll
  for (int st = 1; st < 64; st <<= 1) {
    float An = __shfl_down(As, st, 64);
    float Pn = __shfl_down(Ps, st, 64);
    if (lane + st < 64) { As = As + Ps * An; Ps = Ps * Pn; }
  }
  float G = __shfl_down(As, 1, 64);   // exclusive: lanes l+1..63
  if (lane == 63) G = 0.f;

  if (lane < 32) {                    // first 512 elems are this wave's output
    float g = G;
#pragma unroll
    for (int i = 15; i >= 0; --i) {
      g = d[i] + cf[i] * g;
      const size_t j = (size_t)(idx0 + i);
      float val = out[j * 20 + 19];
      out[j * 20 + 18] = g;
      out[j * 20 + 19] = g + val;
    }
  }
}

// ---------------------------------------------------------------------------
extern "C" void kernel_launch(void* const* d_in, const int* in_sizes, int n_in,
                              void* d_out, int out_size, void* d_ws, size_t ws_size,
                              hipStream_t stream) {
  const float* states      = (const float*)d_in[0];
  const float* next_states = (const float*)d_in[1];
  const float* rewards     = (const float*)d_in[2];
  const float* masks       = (const float*)d_in[3];
  const float* aw1 = (const float*)d_in[4];
  const float* ab1 = (const float*)d_in[5];
  const float* ag1 = (const float*)d_in[6];
  const float* an1 = (const float*)d_in[7];
  const float* aw2 = (const float*)d_in[8];
  const float* ab2 = (const float*)d_in[9];
  const float* ag2 = (const float*)d_in[10];
  const float* an2 = (const float*)d_in[11];
  const float* aw3 = (const float*)d_in[12];
  const float* ab3 = (const float*)d_in[13];
  const float* cw1 = (const float*)d_in[14];
  const float* cb1 = (const float*)d_in[15];
  const float* cg1 = (const float*)d_in[16];
  const float* cn1 = (const float*)d_in[17];
  const float* cw2 = (const float*)d_in[18];
  const float* cb2 = (const float*)d_in[19];
  const float* cg2 = (const float*)d_in[20];
  const float* cn2 = (const float*)d_in[21];
  const float* cw3 = (const float*)d_in[22];
  const float* cb3 = (const float*)d_in[23];

  __hip_bfloat16* wbuf = (__hip_bfloat16*)d_ws;
  float* deltas = (float*)((char*)d_ws + OFF_DELTAS_BYTES);
  float* out = (float*)d_out;

  prep_weights<<<(W_ELEMS + 255) / 256, 256, 0, stream>>>(aw1, aw2, aw3, cw1, cw2, cw3, wbuf);
  mlp_kernel<<<T_SZ / 32, 128, 0, stream>>>(
      states, next_states, rewards, masks,
      ab1, ag1, an1, ab2, ag2, an2, ab3,
      cb1, cg1, cn1, cb2, cg2, cn2, cb3,
      wbuf, deltas, out);
  gae_kernel<<<256, 256, 0, stream>>>(deltas, masks, out);
}